// Round 3
// baseline (231.318 us; speedup 1.0000x reference)
//
#include <hip/hip_runtime.h>

// ChunkwiseRetention: B=8 T=1024 C=1024 NH=16 HD=64
// out[b,t,h*64+d] = GN_b(r)*w[h]+bias[h],  r = (QK^T ∘ decay)V + 1024*Q@past_kv
// current_kv[h] = gamma_h*past_kv[h] + mean_b(K^T V)

#define TKN 8192
#define N3  3072

typedef short short8 __attribute__((ext_vector_type(8)));
typedef float f32x4 __attribute__((ext_vector_type(4)));

static __device__ __forceinline__ unsigned short f2bf(float f){
  unsigned int u = __float_as_uint(f);
  u += 0x7FFFu + ((u >> 16) & 1u);
  return (unsigned short)(u >> 16);
}
static __device__ __forceinline__ float bf2f(unsigned short s){
  return __uint_as_float(((unsigned int)s) << 16);
}
static __device__ __forceinline__ void g2lds16(const void* g, void* l){
  __builtin_amdgcn_global_load_lds(
      (const __attribute__((address_space(1))) unsigned int*)g,
      (__attribute__((address_space(3))) unsigned int*)l, 16, 0, 0);
}

// ---------------- conversions ----------------
__global__ __launch_bounds__(256) void k_cvt_x(const float* __restrict__ x,
                                               unsigned short* __restrict__ xb){
  const int n4 = TKN*1024/4;
  for (int idx = blockIdx.x*256 + threadIdx.x; idx < n4; idx += gridDim.x*256){
    float4 v = reinterpret_cast<const float4*>(x)[idx];
    ushort4 o;
    o.x = f2bf(v.x); o.y = f2bf(v.y); o.z = f2bf(v.z); o.w = f2bf(v.w);
    reinterpret_cast<ushort4*>(xb)[idx] = o;
  }
}

// W [1024][3072] f32 -> WT [3072][1024] bf16
__global__ __launch_bounds__(256) void k_cvt_w(const float* __restrict__ w,
                                               unsigned short* __restrict__ wt){
  __shared__ float tile[64][65];
  const int n0 = blockIdx.x*64, k0 = blockIdx.y*64;
  const int tn = threadIdx.x & 63, t4 = threadIdx.x >> 6;
  for (int kk = t4; kk < 64; kk += 4)
    tile[kk][tn] = w[(k0+kk)*N3 + n0 + tn];
  __syncthreads();
  for (int nn = t4; nn < 64; nn += 4)
    wt[(n0+nn)*1024 + k0 + tn] = f2bf(tile[tn][nn]);
}

// pkt[h][e][d] = past_kv[h][d][e] * 1024  (bf16)
__global__ __launch_bounds__(256) void k_cvt_pk(const float* __restrict__ pk,
                                                unsigned short* __restrict__ pkt){
  int i = blockIdx.x*256 + threadIdx.x;
  int h = i >> 12, e = (i >> 6) & 63, d = i & 63;
  pkt[i] = f2bf(pk[(h<<12) + (d<<6) + e] * 1024.0f);
}

// ---------------- QKV GEMM: 256x128 tile, BK=64, 8-wave, counted-vmcnt pipeline ----------------
__global__ __launch_bounds__(512, 2) void k_gemm(const unsigned short* __restrict__ A,
                                                 const unsigned short* __restrict__ Bt,
                                                 unsigned short* __restrict__ qb,
                                                 unsigned short* __restrict__ kb,
                                                 unsigned short* __restrict__ ktb,
                                                 unsigned short* __restrict__ vtb){
  __shared__ unsigned short As[2][2][8192];   // [buf][kk][256 rows x 32 k] (swizzled)
  __shared__ unsigned short Bs[2][2][4096];   // [buf][kk][128 rows x 32 k] (swizzled)
  const int tid = threadIdx.x;
  const int lane = tid & 63, wid = tid >> 6;
  const int wm = wid >> 1, wn = wid & 1;      // 4 m-waves x 2 n-waves, each 64x64 out
  const int n15 = lane & 15, l4 = lane >> 4;

  // T1: bijective XCD swizzle (768 % 8 == 0)
  const int id = blockIdx.x;
  const int lin = (id & 7) * 96 + (id >> 3);
  const int bm = lin & 31, bn = lin >> 5;     // consecutive lin share the B panel
  const int m0 = bm * 256, n0 = bn * 128;

  const int ar = tid >> 2;                    // staging row 0..127
  const int cg8 = (((tid & 3) ^ ((tid >> 3) & 3)) << 3);  // pre-swizzled k-chunk (T2, rule 21)

  f32x4 acc[4][4] = {};

  // prologue: stage tile 0 (both kk halves) into buf 0
  #pragma unroll
  for (int kk = 0; kk < 2; ++kk){
    const int k0 = kk*32;
    g2lds16(A  + (long)(m0 + ar)*1024       + k0 + cg8, (char*)&As[0][kk][0] + tid*16);
    g2lds16(A  + (long)(m0 + 128 + ar)*1024 + k0 + cg8, (char*)&As[0][kk][0] + 8192 + tid*16);
    g2lds16(Bt + (long)(n0 + ar)*1024       + k0 + cg8, (char*)&Bs[0][kk][0] + tid*16);
  }
  asm volatile("s_waitcnt vmcnt(3)" ::: "memory");
  __builtin_amdgcn_s_barrier();

  #pragma unroll 2
  for (int t = 0; t < 16; ++t){
    const int c = t & 1;
    const int ts = (t < 15) ? t + 1 : 15;     // clamped dummy re-stage on last tile
    #pragma unroll
    for (int kk = 0; kk < 2; ++kk){
      // ds_reads: tile t, k-half kk, from buf c
      short8 a0, a1, a2, a3, b0, b1, b2, b3;
      {
        const char* ab = (const char*)&As[c][kk][0];
        const int r0 = wm*64 + n15;
        const int ka = (l4 ^ ((r0 >> 1) & 3)) << 4;   // (r0+16m)>>1 & 3 is m-invariant
        a0 = *(const short8*)(ab + (r0      )*64 + ka);
        a1 = *(const short8*)(ab + (r0 + 16 )*64 + ka);
        a2 = *(const short8*)(ab + (r0 + 32 )*64 + ka);
        a3 = *(const short8*)(ab + (r0 + 48 )*64 + ka);
        const char* bbp = (const char*)&Bs[c][kk][0];
        const int s0 = wn*64 + n15;
        const int kb2 = (l4 ^ ((s0 >> 1) & 3)) << 4;
        b0 = *(const short8*)(bbp + (s0      )*64 + kb2);
        b1 = *(const short8*)(bbp + (s0 + 16 )*64 + kb2);
        b2 = *(const short8*)(bbp + (s0 + 32 )*64 + kb2);
        b3 = *(const short8*)(bbp + (s0 + 48 )*64 + kb2);
      }
      // stage (tile ts, kk) into buf c^1 (its old content is dead since tile t began)
      {
        const int k0 = ts*64 + kk*32;
        g2lds16(A  + (long)(m0 + ar)*1024       + k0 + cg8, (char*)&As[c^1][kk][0] + tid*16);
        g2lds16(A  + (long)(m0 + 128 + ar)*1024 + k0 + cg8, (char*)&As[c^1][kk][0] + 8192 + tid*16);
        g2lds16(Bt + (long)(n0 + ar)*1024       + k0 + cg8, (char*)&Bs[c^1][kk][0] + tid*16);
      }
      // counted vmcnt: drains the 3 loads issued one phase ago (read next phase)
      asm volatile("s_waitcnt vmcnt(3)" ::: "memory");
      __builtin_amdgcn_s_barrier();
      asm volatile("s_waitcnt lgkmcnt(0)" ::: "memory");
      __builtin_amdgcn_sched_barrier(0);
      __builtin_amdgcn_s_setprio(1);
      acc[0][0] = __builtin_amdgcn_mfma_f32_16x16x32_bf16(a0, b0, acc[0][0], 0,0,0);
      acc[1][0] = __builtin_amdgcn_mfma_f32_16x16x32_bf16(a1, b0, acc[1][0], 0,0,0);
      acc[2][0] = __builtin_amdgcn_mfma_f32_16x16x32_bf16(a2, b0, acc[2][0], 0,0,0);
      acc[3][0] = __builtin_amdgcn_mfma_f32_16x16x32_bf16(a3, b0, acc[3][0], 0,0,0);
      acc[0][1] = __builtin_amdgcn_mfma_f32_16x16x32_bf16(a0, b1, acc[0][1], 0,0,0);
      acc[1][1] = __builtin_amdgcn_mfma_f32_16x16x32_bf16(a1, b1, acc[1][1], 0,0,0);
      acc[2][1] = __builtin_amdgcn_mfma_f32_16x16x32_bf16(a2, b1, acc[2][1], 0,0,0);
      acc[3][1] = __builtin_amdgcn_mfma_f32_16x16x32_bf16(a3, b1, acc[3][1], 0,0,0);
      acc[0][2] = __builtin_amdgcn_mfma_f32_16x16x32_bf16(a0, b2, acc[0][2], 0,0,0);
      acc[1][2] = __builtin_amdgcn_mfma_f32_16x16x32_bf16(a1, b2, acc[1][2], 0,0,0);
      acc[2][2] = __builtin_amdgcn_mfma_f32_16x16x32_bf16(a2, b2, acc[2][2], 0,0,0);
      acc[3][2] = __builtin_amdgcn_mfma_f32_16x16x32_bf16(a3, b2, acc[3][2], 0,0,0);
      acc[0][3] = __builtin_amdgcn_mfma_f32_16x16x32_bf16(a0, b3, acc[0][3], 0,0,0);
      acc[1][3] = __builtin_amdgcn_mfma_f32_16x16x32_bf16(a1, b3, acc[1][3], 0,0,0);
      acc[2][3] = __builtin_amdgcn_mfma_f32_16x16x32_bf16(a2, b3, acc[2][3], 0,0,0);
      acc[3][3] = __builtin_amdgcn_mfma_f32_16x16x32_bf16(a3, b3, acc[3][3], 0,0,0);
      __builtin_amdgcn_s_setprio(0);
      __builtin_amdgcn_s_barrier();
    }
  }

  // epilogue: drain dummy stages, then per-wave conflict-free repack + scatter
  asm volatile("s_waitcnt vmcnt(0)" ::: "memory");
  __syncthreads();

  const int bb = m0 >> 10;
  const int t0g = (m0 & 1023) + wm*64;
  const int which = n0 >> 10;                 // 0=q 1=k 2=v
  const int cw = (n0 & 1023) + wn*64;
  const int h = cw >> 6;                      // 64-col wave region = exactly one head
  char* W = (char*)&As[0][0][0] + wid*8192;   // per-wave 8 KB scratch [64 rows][128 B], XOR-swizzled
  const long bh = (long)(bb*16 + h);

  if (which < 2){                             // row-major [b][h][t][64] for q,k
    unsigned short* dst = which ? kb : qb;
    #pragma unroll
    for (int mi = 0; mi < 4; ++mi)
      #pragma unroll
      for (int nf = 0; nf < 4; ++nf)
        #pragma unroll
        for (int r = 0; r < 4; ++r){
          int row = mi*16 + l4*4 + r;
          int colb = (nf*32 + 2*n15) ^ ((row & 7) << 4);
          *(unsigned short*)(W + row*128 + colb) = f2bf(acc[mi][nf][r]);
        }
    asm volatile("s_waitcnt lgkmcnt(0)" ::: "memory");
    #pragma unroll
    for (int hh = 0; hh < 2; ++hh)
      #pragma unroll
      for (int c2 = 0; c2 < 4; ++c2){
        int row = hh*32 + (lane >> 1);
        int off = ((lane & 1)*64 + c2*16) ^ ((row & 7) << 4);
        uint4 v = *(const uint4*)(W + row*128 + off);
        int dcol = (lane & 1)*32 + c2*8;
        *(uint4*)(&dst[(bh*1024 + t0g + row)*64 + dcol]) = v;
      }
  }
  if (which >= 1){                            // transposed [b][h][d][t] for k,v
    unsigned short* dst = (which == 1) ? ktb : vtb;
    if (which == 1){ asm volatile("s_waitcnt lgkmcnt(0)" ::: "memory"); }
    #pragma unroll
    for (int mi = 0; mi < 4; ++mi)
      #pragma unroll
      for (int nf = 0; nf < 4; ++nf)
        #pragma unroll
        for (int r = 0; r < 4; ++r){
          int dl = nf*16 + n15;
          int row = mi*16 + l4*4 + r;
          int colb = (2*row) ^ ((dl & 7) << 4);
          *(unsigned short*)(W + dl*128 + colb) = f2bf(acc[mi][nf][r]);
        }
    asm volatile("s_waitcnt lgkmcnt(0)" ::: "memory");
    #pragma unroll
    for (int hh = 0; hh < 2; ++hh)
      #pragma unroll
      for (int c2 = 0; c2 < 4; ++c2){
        int dl = hh*32 + (lane >> 1);
        int off = ((lane & 1)*64 + c2*16) ^ ((dl & 7) << 4);
        uint4 v = *(const uint4*)(W + dl*128 + off);
        int tcol = (lane & 1)*32 + c2*8;
        *(uint4*)(&dst[(bh*64 + dl)*1024 + (m0 & 1023) + wm*64 + tcol]) = v;
      }
  }
}

// ---------------- attention: paired q-tiles, double-buffered K/V ----------------
__global__ __launch_bounds__(256) void k_attn(const unsigned short* __restrict__ qb,
                                              const unsigned short* __restrict__ kb,
                                              const unsigned short* __restrict__ vtb,
                                              const unsigned short* __restrict__ pkt,
                                              unsigned short* __restrict__ rb,
                                              float* __restrict__ gnp){
  __shared__ unsigned short Qs[8192];
  __shared__ unsigned short Kd[2][4096];
  __shared__ unsigned short Vd[2][4096];
  __shared__ unsigned short Ps[8192];
  __shared__ float gred[2][4];
  const int qpair = blockIdx.x;
  const int bh = blockIdx.y;
  const int h = bh & 15;
  const int tid = threadIdx.x;
  const int lane = tid & 63, wid = tid >> 6;
  const int n15 = lane & 15, l4 = lane >> 4;
  const unsigned short* qp = qb + (long)bh*65536;
  const unsigned short* kp = kb + (long)bh*65536;
  const unsigned short* vp = vtb + (long)bh*65536;
  const float lg = log2f(1.0f - exp2f(-5.0f - (float)h));
  const int srow = tid >> 3, schunk = tid & 7;

  float cexp[4];
  #pragma unroll
  for (int nf = 0; nf < 4; ++nf)
    cexp[nf] = exp2f(-lg * (float)(nf*16 + n15));

  float gs = 0.f, gq = 0.f;
  unsigned short* rp = rb + (long)bh*65536;

  for (int p = 0; p < 2; ++p){
    const int qt = p ? (7 - qpair) : qpair;
    const int t0 = qt * 128;
    for (int c = 0; c < 4; ++c){
      int r = c*32 + srow;
      int src = schunk ^ (r & 7);
      g2lds16(qp + (long)(t0 + r)*64 + src*8, (char*)Qs + c*4096 + tid*16);
    }
    for (int c = 0; c < 2; ++c){
      int r = c*32 + srow;
      int src = schunk ^ (r & 7);
      g2lds16(pkt + (long)(h*64 + r)*64 + src*8, (char*)Ps + c*4096 + tid*16);
      g2lds16(kp + (long)r*64 + src*8, (char*)Kd[0] + c*4096 + tid*16);
      g2lds16(vp + (long)r*1024 + src*8, (char*)Vd[0] + c*4096 + tid*16);
    }
    asm volatile("s_waitcnt vmcnt(0)" ::: "memory");
    __syncthreads();

    short8 aq[2][2];
    #pragma unroll
    for (int mf = 0; mf < 2; ++mf)
      #pragma unroll
      for (int kk = 0; kk < 2; ++kk){
        int r = wid*32 + mf*16 + n15;
        int sl = (kk*4 + l4) ^ (r & 7);
        aq[mf][kk] = *reinterpret_cast<const short8*>((const char*)Qs + r*128 + sl*16);
      }

    f32x4 o[2][4] = {};
    #pragma unroll
    for (int kk = 0; kk < 2; ++kk){
      short8 bpk[4];
      #pragma unroll
      for (int nf = 0; nf < 4; ++nf){
        int r = nf*16 + n15;
        int sl = (kk*4 + l4) ^ (r & 7);
        bpk[nf] = *reinterpret_cast<const short8*>((const char*)Ps + r*128 + sl*16);
      }
      #pragma unroll
      for (int mf = 0; mf < 2; ++mf)
        #pragma unroll
        for (int nf = 0; nf < 4; ++nf)
          o[mf][nf] = __builtin_amdgcn_mfma_f32_16x16x32_bf16(aq[mf][kk], bpk[nf], o[mf][nf], 0,0,0);
    }
    __syncthreads();

    const int jmax = 2*qt + 1;
    int cur = 0;
    for (int j = 0; j <= jmax; ++j){
      const int kv0 = j*64;
      if (j < jmax){
        const int kvn = kv0 + 64;
        for (int c = 0; c < 2; ++c){
          int r = c*32 + srow;
          int src = schunk ^ (r & 7);
          g2lds16(kp + (long)(kvn + r)*64 + src*8, (char*)Kd[cur^1] + c*4096 + tid*16);
          g2lds16(vp + (long)r*1024 + kvn + src*8, (char*)Vd[cur^1] + c*4096 + tid*16);
        }
      }
      f32x4 s[2][4] = {};
      #pragma unroll
      for (int kk = 0; kk < 2; ++kk){
        short8 bk[4];
        #pragma unroll
        for (int nf = 0; nf < 4; ++nf){
          int r = nf*16 + n15;
          int sl = (kk*4 + l4) ^ (r & 7);
          bk[nf] = *reinterpret_cast<const short8*>((const char*)Kd[cur] + r*128 + sl*16);
        }
        #pragma unroll
        for (int mf = 0; mf < 2; ++mf)
          #pragma unroll
          for (int nf = 0; nf < 4; ++nf)
            s[mf][nf] = __builtin_amdgcn_mfma_f32_16x16x32_bf16(aq[mf][kk], bk[nf], s[mf][nf], 0,0,0);
      }
      float rowf[2][4];
      #pragma unroll
      for (int mf = 0; mf < 2; ++mf){
        int mB = wid*32 + mf*16 + l4*4;
        #pragma unroll
        for (int r = 0; r < 4; ++r)
          rowf[mf][r] = exp2f(lg * (float)(t0 + mB + r - kv0));
      }
      if (kv0 >= t0){
        #pragma unroll
        for (int mf = 0; mf < 2; ++mf){
          int mB = wid*32 + mf*16 + l4*4;
          #pragma unroll
          for (int nf = 0; nf < 4; ++nf){
            int tj = kv0 + nf*16 + n15;
            int n = nf*16 + n15;
            #pragma unroll
            for (int r = 0; r < 4; ++r){
              int ti = t0 + mB + r;
              float val = (ti >= tj) ? s[mf][nf][r] * (rowf[mf][r] * cexp[nf]) : 0.0f;
              int byte = ((mB + r)*128 + n*2) ^ (((mB + r) & 7) << 4);
              *(unsigned short*)((char*)Ps + byte) = f2bf(val);
            }
          }
        }
      } else {
        #pragma unroll
        for (int mf = 0; mf < 2; ++mf){
          int mB = wid*32 + mf*16 + l4*4;
          #pragma unroll
          for (int nf = 0; nf < 4; ++nf){
            int n = nf*16 + n15;
            #pragma unroll
            for (int r = 0; r < 4; ++r){
              float val = s[mf][nf][r] * (rowf[mf][r] * cexp[nf]);
              int byte = ((mB + r)*128 + n*2) ^ (((mB + r) & 7) << 4);
              *(unsigned short*)((char*)Ps + byte) = f2bf(val);
            }
          }
        }
      }
      #pragma unroll
      for (int kk = 0; kk < 2; ++kk){
        short8 ap[2], bv[4];
        #pragma unroll
        for (int mf = 0; mf < 2; ++mf){
          int r = wid*32 + mf*16 + n15;
          int sl = (kk*4 + l4) ^ (r & 7);
          ap[mf] = *reinterpret_cast<const short8*>((const char*)Ps + r*128 + sl*16);
        }
        #pragma unroll
        for (int nf = 0; nf < 4; ++nf){
          int r = nf*16 + n15;
          int sl = (kk*4 + l4) ^ (r & 7);
          bv[nf] = *reinterpret_cast<const short8*>((const char*)Vd[cur] + r*128 + sl*16);
        }
        #pragma unroll
        for (int mf = 0; mf < 2; ++mf)
          #pragma unroll
          for (int nf = 0; nf < 4; ++nf)
            o[mf][nf] = __builtin_amdgcn_mfma_f32_16x16x32_bf16(ap[mf], bv[nf], o[mf][nf], 0,0,0);
      }
      asm volatile("s_waitcnt vmcnt(0)" ::: "memory");
      __syncthreads();
      cur ^= 1;
    }
    #pragma unroll
    for (int mf = 0; mf < 2; ++mf)
      #pragma unroll
      for (int nf = 0; nf < 4; ++nf)
        #pragma unroll
        for (int r = 0; r < 4; ++r){
          int t = t0 + wid*32 + mf*16 + l4*4 + r;
          int d = nf*16 + n15;
          float v = o[mf][nf][r];
          rp[t*64 + d] = f2bf(v);
          gs += v; gq += v*v;
        }
  }
  #pragma unroll
  for (int off = 32; off > 0; off >>= 1){
    gs += __shfl_down(gs, off);
    gq += __shfl_down(gq, off);
  }
  if (lane == 0){ gred[0][wid] = gs; gred[1][wid] = gq; }
  __syncthreads();
  if (tid == 0){
    gnp[(bh*4 + qpair)*2]   = gred[0][0]+gred[0][1]+gred[0][2]+gred[0][3];
    gnp[(bh*4 + qpair)*2+1] = gred[1][0]+gred[1][1]+gred[1][2]+gred[1][3];
  }
}

// ---------------- K^T V via MFMA ----------------
__global__ __launch_bounds__(256) void k_kvpart(const unsigned short* __restrict__ ktb,
                                                const unsigned short* __restrict__ vtb,
                                                float* __restrict__ part){
  const int tw = blockIdx.x;
  const int bh = blockIdx.y;
  const int tid = threadIdx.x;
  const int lane = tid & 63, wid = tid >> 6;
  const int n15 = lane & 15, l4 = lane >> 4;
  const unsigned short* kt = ktb + (long)bh*65536;
  const unsigned short* vt = vtb + (long)bh*65536;
  const int tb = tw*512 + wid*128;
  f32x4 acc[4][4] = {};
  for (int ks = 0; ks < 4; ++ks){
    const int toff = tb + ks*32 + l4*8;
    short8 a[4], b[4];
    #pragma unroll
    for (int i = 0; i < 4; ++i){
      a[i] = *reinterpret_cast<const short8*>(kt + (long)(i*16 + n15)*1024 + toff);
      b[i] = *reinterpret_cast<const short8*>(vt + (long)(i*16 + n15)*1024 + toff);
    }
    #pragma unroll
    for (int i = 0; i < 4; ++i)
      #pragma unroll
      for (int jn = 0; jn < 4; ++jn)
        acc[i][jn] = __builtin_amdgcn_mfma_f32_16x16x32_bf16(a[i], b[jn], acc[i][jn], 0,0,0);
  }
  float* pp = part + ((long)(bh*8 + tw*4 + wid) << 12);
  #pragma unroll
  for (int i = 0; i < 4; ++i)
    #pragma unroll
    for (int jn = 0; jn < 4; ++jn)
      #pragma unroll
      for (int r = 0; r < 4; ++r)
        pp[(i*16 + l4*4 + r)*64 + jn*16 + n15] = acc[i][jn][r];
}

__global__ __launch_bounds__(256) void k_kvfin(const float* __restrict__ part,
                                               const float* __restrict__ pk,
                                               float* __restrict__ okv){
  int i = blockIdx.x*256 + threadIdx.x;
  int h = i >> 12, de = i & 4095;
  float acc = 0.f;
  for (int b = 0; b < 8; ++b){
    const float* pp = part + (((long)(b*16 + h)*8) << 12) + de;
    #pragma unroll
    for (int w = 0; w < 8; ++w) acc += pp[w*4096];
  }
  float gamma = 1.0f - exp2f(-5.0f - (float)h);
  okv[i] = gamma * pk[i] + acc * 0.125f;
}

// ---------------- GroupNorm finalize ----------------
__global__ __launch_bounds__(64) void k_gnr2(const float* __restrict__ gnp,
                                             float* __restrict__ musig){
  int b = threadIdx.x;
  if (b < 8){
    float S = 0.f, Q = 0.f;
    for (int g = 0; g < 64; ++g){ S += gnp[b*128 + g*2]; Q += gnp[b*128 + g*2 + 1]; }
    float mu  = S * (1.0f/1048576.0f);
    float var = Q * (1.0f/1048576.0f) - mu*mu;
    musig[b*2]   = mu;
    musig[b*2+1] = rsqrtf(var + 1e-5f);
  }
}

__global__ __launch_bounds__(256) void k_gnnorm(const unsigned short* __restrict__ rbuf,
                                                const float* __restrict__ musig,
                                                const float* __restrict__ gw,
                                                const float* __restrict__ gb,
                                                float* __restrict__ out){
  const int n8 = TKN*1024/8;
  for (int idx = blockIdx.x*256 + threadIdx.x; idx < n8; idx += gridDim.x*256){
    int o = idx*8;
    int c = o & 1023;
    int t = (o >> 10) & 1023;
    int b = o >> 20;
    int h = c >> 6, d = c & 63;
    short8 v = *reinterpret_cast<const short8*>(rbuf + ((long)(b*16 + h) << 16) + t*64 + d);
    float rs = musig[b*2+1];
    float a = gw[h]*rs, b2 = gb[h] - musig[b*2]*a;
    float4 o0, o1;
    o0.x = bf2f((unsigned short)v[0])*a + b2;
    o0.y = bf2f((unsigned short)v[1])*a + b2;
    o0.z = bf2f((unsigned short)v[2])*a + b2;
    o0.w = bf2f((unsigned short)v[3])*a + b2;
    o1.x = bf2f((unsigned short)v[4])*a + b2;
    o1.y = bf2f((unsigned short)v[5])*a + b2;
    o1.z = bf2f((unsigned short)v[6])*a + b2;
    o1.w = bf2f((unsigned short)v[7])*a + b2;
    *reinterpret_cast<float4*>(out + o)     = o0;
    *reinterpret_cast<float4*>(out + o + 4) = o1;
  }
}

extern "C" void kernel_launch(void* const* d_in, const int* in_sizes, int n_in,
                              void* d_out, int out_size, void* d_ws, size_t ws_size,
                              hipStream_t stream){
  const float* x  = (const float*)d_in[0];
  const float* pk = (const float*)d_in[1];
  const float* w  = (const float*)d_in[2];
  const float* gw = (const float*)d_in[3];
  const float* gb = (const float*)d_in[4];
  float* out = (float*)d_out;
  char* ws = (char*)d_ws;

  unsigned short* Xb  = (unsigned short*)(ws);
  unsigned short* WTb = (unsigned short*)(ws + 16777216);
  unsigned short* Qb  = (unsigned short*)(ws + 23068672);
  unsigned short* Kb  = (unsigned short*)(ws + 39845888);
  unsigned short* VTb = (unsigned short*)(ws + 56623104);
  unsigned short* KTb = (unsigned short*)(ws + 73400320);
  unsigned short* PKt = (unsigned short*)(ws + 90177536);
  unsigned short* Rb  = (unsigned short*)(ws + 90308608);
  float* KVp = (float*)(ws);                                   // aliases Xb (dead after gemm)
  float* GNp = (float*)(ws + 107085824);
  float* MuS = (float*)(ws + 107089920);

  k_cvt_x  <<<dim3(2048),    dim3(256), 0, stream>>>(x, Xb);
  k_cvt_w  <<<dim3(48, 16),  dim3(256), 0, stream>>>(w, WTb);
  k_cvt_pk <<<dim3(256),     dim3(256), 0, stream>>>(pk, PKt);
  k_gemm   <<<dim3(768),     dim3(512), 0, stream>>>(Xb, WTb, Qb, Kb, KTb, VTb);
  k_attn   <<<dim3(4, 128),  dim3(256), 0, stream>>>(Qb, Kb, VTb, PKt, Rb, GNp);
  k_kvpart <<<dim3(2, 128),  dim3(256), 0, stream>>>(KTb, VTb, KVp);
  k_kvfin  <<<dim3(256),     dim3(256), 0, stream>>>(KVp, pk, out + 8388608);
  k_gnr2   <<<dim3(1),       dim3(64),  0, stream>>>(GNp, MuS);
  k_gnnorm <<<dim3(1024),    dim3(256), 0, stream>>>(Rb, MuS, gw, gb, out);
}

// Round 4
// 202.199 us; speedup vs baseline: 1.1440x; 1.1440x over previous
//
#include <hip/hip_runtime.h>

// ChunkwiseRetention: B=8 T=1024 C=1024 NH=16 HD=64
// out[b,t,h*64+d] = GN_b(r)*w[h]+bias[h],  r = (QK^T ∘ decay)V + 1024*Q@past_kv
// current_kv[h] = gamma_h*past_kv[h] + mean_b(K^T V)

#define TKN 8192
#define N3  3072

typedef short short8 __attribute__((ext_vector_type(8)));
typedef float f32x4 __attribute__((ext_vector_type(4)));

static __device__ __forceinline__ unsigned short f2bf(float f){
  unsigned int u = __float_as_uint(f);
  u += 0x7FFFu + ((u >> 16) & 1u);
  return (unsigned short)(u >> 16);
}
static __device__ __forceinline__ float bf2f(unsigned short s){
  return __uint_as_float(((unsigned int)s) << 16);
}
static __device__ __forceinline__ void g2lds16(const void* g, void* l){
  __builtin_amdgcn_global_load_lds(
      (const __attribute__((address_space(1))) unsigned int*)g,
      (__attribute__((address_space(3))) unsigned int*)l, 16, 0, 0);
}

// ---------------- conversions ----------------
__global__ __launch_bounds__(256) void k_cvt_x(const float* __restrict__ x,
                                               unsigned short* __restrict__ xb){
  const int n4 = TKN*1024/4;
  for (int idx = blockIdx.x*256 + threadIdx.x; idx < n4; idx += gridDim.x*256){
    float4 v = reinterpret_cast<const float4*>(x)[idx];
    ushort4 o;
    o.x = f2bf(v.x); o.y = f2bf(v.y); o.z = f2bf(v.z); o.w = f2bf(v.w);
    reinterpret_cast<ushort4*>(xb)[idx] = o;
  }
}

// W [1024][3072] f32 -> WT [3072][1024] bf16
__global__ __launch_bounds__(256) void k_cvt_w(const float* __restrict__ w,
                                               unsigned short* __restrict__ wt){
  __shared__ float tile[64][65];
  const int n0 = blockIdx.x*64, k0 = blockIdx.y*64;
  const int tn = threadIdx.x & 63, t4 = threadIdx.x >> 6;
  for (int kk = t4; kk < 64; kk += 4)
    tile[kk][tn] = w[(k0+kk)*N3 + n0 + tn];
  __syncthreads();
  for (int nn = t4; nn < 64; nn += 4)
    wt[(n0+nn)*1024 + k0 + tn] = f2bf(tile[tn][nn]);
}

// pkt[h][e][d] = past_kv[h][d][e] * 1024  (bf16)
__global__ __launch_bounds__(256) void k_cvt_pk(const float* __restrict__ pk,
                                                unsigned short* __restrict__ pkt){
  int i = blockIdx.x*256 + threadIdx.x;
  int h = i >> 12, e = (i >> 6) & 63, d = i & 63;
  pkt[i] = f2bf(pk[(h<<12) + (d<<6) + e] * 1024.0f);
}

// ---------------- QKV GEMM (bf16 MFMA, 128x128 tile, BK=64, m97 structure) ----------------
__global__ __launch_bounds__(256) void k_gemm(const unsigned short* __restrict__ A,
                                              const unsigned short* __restrict__ Bt,
                                              unsigned short* __restrict__ qb,
                                              unsigned short* __restrict__ kb,
                                              unsigned short* __restrict__ vtb){
  __shared__ unsigned short smem[16384];          // As(16KB)+Bs(16KB) | 4x8KB wave scratch
  unsigned short* As = smem;
  unsigned short* Bs = smem + 8192;
  const int tid = threadIdx.x;
  const int lane = tid & 63, wid = tid >> 6;
  const int wm = wid >> 1, wn = wid & 1;
  const int n15 = lane & 15, l4 = lane >> 4;
  const int m0 = blockIdx.y * 128;
  const int n0 = blockIdx.x * 128;

  f32x4 acc[4][4] = {};
  const int srow = tid >> 3, schunk = tid & 7;

  for (int kt = 0; kt < 16; ++kt){
    const int k0 = kt * 64;
    __syncthreads();
    for (int c = 0; c < 4; ++c){
      int r = c*32 + srow;
      int src = schunk ^ (r & 7);                 // pre-swizzled global source
      g2lds16(A  + (long)(m0 + r)*1024 + k0 + src*8, (char*)As + c*4096 + tid*16);
      g2lds16(Bt + (long)(n0 + r)*1024 + k0 + src*8, (char*)Bs + c*4096 + tid*16);
    }
    asm volatile("s_waitcnt vmcnt(0)" ::: "memory");
    __syncthreads();
    #pragma unroll
    for (int kk = 0; kk < 2; ++kk){
      short8 a[4], b[4];
      #pragma unroll
      for (int i = 0; i < 4; ++i){
        int ra = wm*64 + i*16 + n15;
        int sa = (kk*4 + l4) ^ (ra & 7);
        a[i] = *reinterpret_cast<const short8*>((const char*)As + ra*128 + sa*16);
        int rb = wn*64 + i*16 + n15;
        int sb = (kk*4 + l4) ^ (rb & 7);
        b[i] = *reinterpret_cast<const short8*>((const char*)Bs + rb*128 + sb*16);
      }
      #pragma unroll
      for (int i = 0; i < 4; ++i)
        #pragma unroll
        for (int j = 0; j < 4; ++j)
          acc[i][j] = __builtin_amdgcn_mfma_f32_16x16x32_bf16(a[i], b[j], acc[i][j], 0, 0, 0);
    }
  }
  __syncthreads();                                // all waves done with As/Bs

  // conflict-free per-wave epilogue: 8KB scratch [64 rows][128B], XOR-swizzled
  const int bb = m0 >> 10;
  const int which = n0 >> 10;                     // 0=q 1=k 2=v
  const int cw = (n0 & 1023) + wn*64;
  const int h = cw >> 6;                          // wave's 64 cols = one head
  const long bh = (long)(bb*16 + h);
  const int trow0 = (m0 & 1023) + wm*64;
  char* W = (char*)smem + wid*8192;

  if (which < 2){                                 // q,k row-major [b][h][t][64]
    unsigned short* dst = which ? kb : qb;
    #pragma unroll
    for (int mi = 0; mi < 4; ++mi)
      #pragma unroll
      for (int nf = 0; nf < 4; ++nf)
        #pragma unroll
        for (int r = 0; r < 4; ++r){
          int row = mi*16 + l4*4 + r;
          int colb = (nf*32 + 2*n15) ^ ((row & 7) << 4);
          *(unsigned short*)(W + row*128 + colb) = f2bf(acc[mi][nf][r]);
        }
    asm volatile("s_waitcnt lgkmcnt(0)" ::: "memory");
    #pragma unroll
    for (int hh = 0; hh < 2; ++hh)
      #pragma unroll
      for (int c2 = 0; c2 < 4; ++c2){
        int row = hh*32 + (lane >> 1);
        int off = ((lane & 1)*64 + c2*16) ^ ((row & 7) << 4);
        uint4 v = *(const uint4*)(W + row*128 + off);
        int dcol = (lane & 1)*32 + c2*8;
        *(uint4*)(&dst[(bh*1024 + trow0 + row)*64 + dcol]) = v;
      }
  } else {                                        // v transposed [b][h][d][t]
    #pragma unroll
    for (int mi = 0; mi < 4; ++mi)
      #pragma unroll
      for (int nf = 0; nf < 4; ++nf)
        #pragma unroll
        for (int r = 0; r < 4; ++r){
          int dl = nf*16 + n15;
          int row = mi*16 + l4*4 + r;
          int colb = (2*row) ^ ((dl & 7) << 4);
          *(unsigned short*)(W + dl*128 + colb) = f2bf(acc[mi][nf][r]);
        }
    asm volatile("s_waitcnt lgkmcnt(0)" ::: "memory");
    #pragma unroll
    for (int hh = 0; hh < 2; ++hh)
      #pragma unroll
      for (int c2 = 0; c2 < 4; ++c2){
        int dl = hh*32 + (lane >> 1);
        int off = ((lane & 1)*64 + c2*16) ^ ((dl & 7) << 4);
        uint4 v = *(const uint4*)(W + dl*128 + off);
        int tcol = (lane & 1)*32 + c2*8;
        *(uint4*)(&vtb[(bh*64 + dl)*1024 + trow0 + tcol]) = v;
      }
  }
}

// ---------------- attention: paired q-tiles, double-buffered K/V ----------------
__global__ __launch_bounds__(256) void k_attn(const unsigned short* __restrict__ qb,
                                              const unsigned short* __restrict__ kb,
                                              const unsigned short* __restrict__ vtb,
                                              const unsigned short* __restrict__ pkt,
                                              unsigned short* __restrict__ rb,
                                              float* __restrict__ gnp){
  __shared__ unsigned short Qs[8192];
  __shared__ unsigned short Kd[2][4096];
  __shared__ unsigned short Vd[2][4096];
  __shared__ unsigned short Ps[8192];
  __shared__ float gred[2][4];
  const int qpair = blockIdx.x;
  const int bh = blockIdx.y;
  const int h = bh & 15;
  const int tid = threadIdx.x;
  const int lane = tid & 63, wid = tid >> 6;
  const int n15 = lane & 15, l4 = lane >> 4;
  const unsigned short* qp = qb + (long)bh*65536;
  const unsigned short* kp = kb + (long)bh*65536;
  const unsigned short* vp = vtb + (long)bh*65536;
  const float lg = log2f(1.0f - exp2f(-5.0f - (float)h));
  const int srow = tid >> 3, schunk = tid & 7;

  float cexp[4];
  #pragma unroll
  for (int nf = 0; nf < 4; ++nf)
    cexp[nf] = exp2f(-lg * (float)(nf*16 + n15));

  float gs = 0.f, gq = 0.f;
  unsigned short* rp = rb + (long)bh*65536;

  for (int p = 0; p < 2; ++p){
    const int qt = p ? (7 - qpair) : qpair;
    const int t0 = qt * 128;
    for (int c = 0; c < 4; ++c){
      int r = c*32 + srow;
      int src = schunk ^ (r & 7);
      g2lds16(qp + (long)(t0 + r)*64 + src*8, (char*)Qs + c*4096 + tid*16);
    }
    for (int c = 0; c < 2; ++c){
      int r = c*32 + srow;
      int src = schunk ^ (r & 7);
      g2lds16(pkt + (long)(h*64 + r)*64 + src*8, (char*)Ps + c*4096 + tid*16);
      g2lds16(kp + (long)r*64 + src*8, (char*)Kd[0] + c*4096 + tid*16);
      g2lds16(vp + (long)r*1024 + src*8, (char*)Vd[0] + c*4096 + tid*16);
    }
    asm volatile("s_waitcnt vmcnt(0)" ::: "memory");
    __syncthreads();

    short8 aq[2][2];
    #pragma unroll
    for (int mf = 0; mf < 2; ++mf)
      #pragma unroll
      for (int kk = 0; kk < 2; ++kk){
        int r = wid*32 + mf*16 + n15;
        int sl = (kk*4 + l4) ^ (r & 7);
        aq[mf][kk] = *reinterpret_cast<const short8*>((const char*)Qs + r*128 + sl*16);
      }

    f32x4 o[2][4] = {};
    #pragma unroll
    for (int kk = 0; kk < 2; ++kk){
      short8 bpk[4];
      #pragma unroll
      for (int nf = 0; nf < 4; ++nf){
        int r = nf*16 + n15;
        int sl = (kk*4 + l4) ^ (r & 7);
        bpk[nf] = *reinterpret_cast<const short8*>((const char*)Ps + r*128 + sl*16);
      }
      #pragma unroll
      for (int mf = 0; mf < 2; ++mf)
        #pragma unroll
        for (int nf = 0; nf < 4; ++nf)
          o[mf][nf] = __builtin_amdgcn_mfma_f32_16x16x32_bf16(aq[mf][kk], bpk[nf], o[mf][nf], 0,0,0);
    }
    __syncthreads();

    const int jmax = 2*qt + 1;
    int cur = 0;
    for (int j = 0; j <= jmax; ++j){
      const int kv0 = j*64;
      if (j < jmax){
        const int kvn = kv0 + 64;
        for (int c = 0; c < 2; ++c){
          int r = c*32 + srow;
          int src = schunk ^ (r & 7);
          g2lds16(kp + (long)(kvn + r)*64 + src*8, (char*)Kd[cur^1] + c*4096 + tid*16);
          g2lds16(vp + (long)r*1024 + kvn + src*8, (char*)Vd[cur^1] + c*4096 + tid*16);
        }
      }
      f32x4 s[2][4] = {};
      #pragma unroll
      for (int kk = 0; kk < 2; ++kk){
        short8 bk[4];
        #pragma unroll
        for (int nf = 0; nf < 4; ++nf){
          int r = nf*16 + n15;
          int sl = (kk*4 + l4) ^ (r & 7);
          bk[nf] = *reinterpret_cast<const short8*>((const char*)Kd[cur] + r*128 + sl*16);
        }
        #pragma unroll
        for (int mf = 0; mf < 2; ++mf)
          #pragma unroll
          for (int nf = 0; nf < 4; ++nf)
            s[mf][nf] = __builtin_amdgcn_mfma_f32_16x16x32_bf16(aq[mf][kk], bk[nf], s[mf][nf], 0,0,0);
      }
      float rowf[2][4];
      #pragma unroll
      for (int mf = 0; mf < 2; ++mf){
        int mB = wid*32 + mf*16 + l4*4;
        #pragma unroll
        for (int r = 0; r < 4; ++r)
          rowf[mf][r] = exp2f(lg * (float)(t0 + mB + r - kv0));
      }
      if (kv0 >= t0){
        #pragma unroll
        for (int mf = 0; mf < 2; ++mf){
          int mB = wid*32 + mf*16 + l4*4;
          #pragma unroll
          for (int nf = 0; nf < 4; ++nf){
            int tj = kv0 + nf*16 + n15;
            int n = nf*16 + n15;
            #pragma unroll
            for (int r = 0; r < 4; ++r){
              int ti = t0 + mB + r;
              float val = (ti >= tj) ? s[mf][nf][r] * (rowf[mf][r] * cexp[nf]) : 0.0f;
              int byte = ((mB + r)*128 + n*2) ^ (((mB + r) & 7) << 4);
              *(unsigned short*)((char*)Ps + byte) = f2bf(val);
            }
          }
        }
      } else {
        #pragma unroll
        for (int mf = 0; mf < 2; ++mf){
          int mB = wid*32 + mf*16 + l4*4;
          #pragma unroll
          for (int nf = 0; nf < 4; ++nf){
            int n = nf*16 + n15;
            #pragma unroll
            for (int r = 0; r < 4; ++r){
              float val = s[mf][nf][r] * (rowf[mf][r] * cexp[nf]);
              int byte = ((mB + r)*128 + n*2) ^ (((mB + r) & 7) << 4);
              *(unsigned short*)((char*)Ps + byte) = f2bf(val);
            }
          }
        }
      }
      #pragma unroll
      for (int kk = 0; kk < 2; ++kk){
        short8 ap[2], bv[4];
        #pragma unroll
        for (int mf = 0; mf < 2; ++mf){
          int r = wid*32 + mf*16 + n15;
          int sl = (kk*4 + l4) ^ (r & 7);
          ap[mf] = *reinterpret_cast<const short8*>((const char*)Ps + r*128 + sl*16);
        }
        #pragma unroll
        for (int nf = 0; nf < 4; ++nf){
          int r = nf*16 + n15;
          int sl = (kk*4 + l4) ^ (r & 7);
          bv[nf] = *reinterpret_cast<const short8*>((const char*)Vd[cur] + r*128 + sl*16);
        }
        #pragma unroll
        for (int mf = 0; mf < 2; ++mf)
          #pragma unroll
          for (int nf = 0; nf < 4; ++nf)
            o[mf][nf] = __builtin_amdgcn_mfma_f32_16x16x32_bf16(ap[mf], bv[nf], o[mf][nf], 0,0,0);
      }
      asm volatile("s_waitcnt vmcnt(0)" ::: "memory");
      __syncthreads();
      cur ^= 1;
    }
    #pragma unroll
    for (int mf = 0; mf < 2; ++mf)
      #pragma unroll
      for (int nf = 0; nf < 4; ++nf)
        #pragma unroll
        for (int r = 0; r < 4; ++r){
          int t = t0 + wid*32 + mf*16 + l4*4 + r;
          int d = nf*16 + n15;
          float v = o[mf][nf][r];
          rp[t*64 + d] = f2bf(v);
          gs += v; gq += v*v;
        }
  }
  #pragma unroll
  for (int off = 32; off > 0; off >>= 1){
    gs += __shfl_down(gs, off);
    gq += __shfl_down(gq, off);
  }
  if (lane == 0){ gred[0][wid] = gs; gred[1][wid] = gq; }
  __syncthreads();
  if (tid == 0){
    gnp[(bh*4 + qpair)*2]   = gred[0][0]+gred[0][1]+gred[0][2]+gred[0][3];
    gnp[(bh*4 + qpair)*2+1] = gred[1][0]+gred[1][1]+gred[1][2]+gred[1][3];
  }
}

// ---------------- K^T V partials (LDS-transpose vector-FMA) ----------------
__global__ __launch_bounds__(256) void k_kvpart(const unsigned short* __restrict__ kb,
                                                const unsigned short* __restrict__ vtb,
                                                float* __restrict__ part){
  __shared__ unsigned short Kt[64*64];            // [t][d]
  __shared__ unsigned int   Vt32[64*33];          // [e][t] padded rows (66 ushorts)
  const int tc = blockIdx.x, bh = blockIdx.y;
  const int tid = threadIdx.x;
  const int d0 = (tid >> 4) << 2;
  const int e0 = (tid & 15) << 2;
  const unsigned short* kp = kb + (long)bh*65536;
  const unsigned short* vp = vtb + (long)bh*65536;
  float acc[4][4] = {{0.f}};
  for (int tt = 0; tt < 4; ++tt){
    const int tb = tc*256 + tt*64;
    __syncthreads();
    {
      int rr0 = tid >> 3, off = (tid & 7) * 8;
      for (int c = 0; c < 2; ++c){
        int r = c*32 + rr0;
        *reinterpret_cast<uint4*>(&Kt[r*64 + off]) =
            *reinterpret_cast<const uint4*>(&kp[(long)(tb + r)*64 + off]);
        uint4 vv = *reinterpret_cast<const uint4*>(&vp[(long)r*1024 + tb + off]);
        unsigned int* dv = &Vt32[r*33 + (off >> 1)];
        dv[0] = vv.x; dv[1] = vv.y; dv[2] = vv.z; dv[3] = vv.w;
      }
    }
    __syncthreads();
    const unsigned short* Vt = (const unsigned short*)Vt32;
    for (int t = 0; t < 64; ++t){
      float kv[4], vv[4];
      #pragma unroll
      for (int i = 0; i < 4; ++i) kv[i] = bf2f(Kt[t*64 + d0 + i]);
      #pragma unroll
      for (int i = 0; i < 4; ++i) vv[i] = bf2f(Vt[(e0 + i)*66 + t]);
      #pragma unroll
      for (int i = 0; i < 4; ++i)
        #pragma unroll
        for (int j = 0; j < 4; ++j) acc[i][j] += kv[i]*vv[j];
    }
  }
  float* pp = part + ((long)(tc*128 + bh) << 12);
  for (int i = 0; i < 4; ++i)
    for (int j = 0; j < 4; ++j)
      pp[(d0+i)*64 + e0 + j] = acc[i][j];
}

__global__ __launch_bounds__(256) void k_kvfin(const float* __restrict__ part,
                                               const float* __restrict__ pk,
                                               float* __restrict__ okv){
  int i = blockIdx.x*256 + threadIdx.x;           // 65536
  int h = i >> 12;
  float acc = 0.f;
  for (int tc = 0; tc < 4; ++tc)
    for (int b = 0; b < 8; ++b)
      acc += part[((long)(tc*128 + b*16 + h) << 12) + (i & 4095)];
  float gamma = 1.0f - exp2f(-5.0f - (float)h);
  okv[i] = gamma * pk[i] + acc * 0.125f;
}

// ---------------- GroupNorm finalize ----------------
__global__ __launch_bounds__(64) void k_gnr2(const float* __restrict__ gnp,
                                             float* __restrict__ musig){
  int b = threadIdx.x;
  if (b < 8){
    float S = 0.f, Q = 0.f;
    for (int g = 0; g < 64; ++g){ S += gnp[b*128 + g*2]; Q += gnp[b*128 + g*2 + 1]; }
    float mu  = S * (1.0f/1048576.0f);
    float var = Q * (1.0f/1048576.0f) - mu*mu;
    musig[b*2]   = mu;
    musig[b*2+1] = rsqrtf(var + 1e-5f);
  }
}

__global__ __launch_bounds__(256) void k_gnnorm(const unsigned short* __restrict__ rbuf,
                                                const float* __restrict__ musig,
                                                const float* __restrict__ gw,
                                                const float* __restrict__ gb,
                                                float* __restrict__ out){
  const int n8 = TKN*1024/8;
  for (int idx = blockIdx.x*256 + threadIdx.x; idx < n8; idx += gridDim.x*256){
    int o = idx*8;
    int c = o & 1023;
    int t = (o >> 10) & 1023;
    int b = o >> 20;
    int h = c >> 6, d = c & 63;
    short8 v = *reinterpret_cast<const short8*>(rbuf + ((long)(b*16 + h) << 16) + t*64 + d);
    float rs = musig[b*2+1];
    float a = gw[h]*rs, b2 = gb[h] - musig[b*2]*a;
    float4 o0, o1;
    o0.x = bf2f((unsigned short)v[0])*a + b2;
    o0.y = bf2f((unsigned short)v[1])*a + b2;
    o0.z = bf2f((unsigned short)v[2])*a + b2;
    o0.w = bf2f((unsigned short)v[3])*a + b2;
    o1.x = bf2f((unsigned short)v[4])*a + b2;
    o1.y = bf2f((unsigned short)v[5])*a + b2;
    o1.z = bf2f((unsigned short)v[6])*a + b2;
    o1.w = bf2f((unsigned short)v[7])*a + b2;
    *reinterpret_cast<float4*>(out + o)     = o0;
    *reinterpret_cast<float4*>(out + o + 4) = o1;
  }
}

extern "C" void kernel_launch(void* const* d_in, const int* in_sizes, int n_in,
                              void* d_out, int out_size, void* d_ws, size_t ws_size,
                              hipStream_t stream){
  const float* x  = (const float*)d_in[0];
  const float* pk = (const float*)d_in[1];
  const float* w  = (const float*)d_in[2];
  const float* gw = (const float*)d_in[3];
  const float* gb = (const float*)d_in[4];
  float* out = (float*)d_out;
  char* ws = (char*)d_ws;

  unsigned short* Xb  = (unsigned short*)(ws);                 // 16 MB (aliased by KVp later)
  unsigned short* WTb = (unsigned short*)(ws + 16777216);      //  6 MB
  unsigned short* Qb  = (unsigned short*)(ws + 23068672);      // 16 MB
  unsigned short* Kb  = (unsigned short*)(ws + 39845888);      // 16 MB
  unsigned short* VTb = (unsigned short*)(ws + 56623104);      // 16 MB
  unsigned short* PKt = (unsigned short*)(ws + 73400320);      // 128 KB
  unsigned short* Rb  = (unsigned short*)(ws + 73531392);      // 16 MB (bf16)
  float* KVp = (float*)(ws);                                   // 8 MB, aliases Xb (dead after gemm)
  float* GNp = (float*)(ws + 90308608);                        // 4 KB
  float* MuS = (float*)(ws + 90312704);                        // 64 B

  k_cvt_x  <<<dim3(2048),    dim3(256), 0, stream>>>(x, Xb);
  k_cvt_w  <<<dim3(48, 16),  dim3(256), 0, stream>>>(w, WTb);
  k_cvt_pk <<<dim3(256),     dim3(256), 0, stream>>>(pk, PKt);
  k_gemm   <<<dim3(24, 64),  dim3(256), 0, stream>>>(Xb, WTb, Qb, Kb, VTb);
  k_attn   <<<dim3(4, 128),  dim3(256), 0, stream>>>(Qb, Kb, VTb, PKt, Rb, GNp);
  k_kvpart <<<dim3(4, 128),  dim3(256), 0, stream>>>(Kb, VTb, KVp);
  k_kvfin  <<<dim3(256),     dim3(256), 0, stream>>>(KVp, pk, out + 8388608);
  k_gnr2   <<<dim3(1),       dim3(64),  0, stream>>>(GNp, MuS);
  k_gnnorm <<<dim3(1024),    dim3(256), 0, stream>>>(Rb, MuS, gw, gb, out);
}

// Round 5
// 183.555 us; speedup vs baseline: 1.2602x; 1.1016x over previous
//
#include <hip/hip_runtime.h>

// ChunkwiseRetention: B=8 T=1024 C=1024 NH=16 HD=64
// out[b,t,h*64+d] = GN_b(r)*w[h]+bias[h],  r = (QK^T ∘ decay)V + 1024*Q@past_kv
// current_kv[h] = gamma_h*past_kv[h] + mean_b(K^T V)

#define TKN 8192
#define N3  3072

typedef short short8 __attribute__((ext_vector_type(8)));
typedef float f32x4 __attribute__((ext_vector_type(4)));

static __device__ __forceinline__ unsigned short f2bf(float f){
  unsigned int u = __float_as_uint(f);
  u += 0x7FFFu + ((u >> 16) & 1u);
  return (unsigned short)(u >> 16);
}
static __device__ __forceinline__ float bf2f(unsigned short s){
  return __uint_as_float(((unsigned int)s) << 16);
}
static __device__ __forceinline__ void g2lds16(const void* g, void* l){
  __builtin_amdgcn_global_load_lds(
      (const __attribute__((address_space(1))) unsigned int*)g,
      (__attribute__((address_space(3))) unsigned int*)l, 16, 0, 0);
}

// ---------------- merged conversions ----------------
// blocks [0,2048): x f32->bf16 ; [2048,2816): W transpose ; [2816,3072): past_kv^T
__global__ __launch_bounds__(256) void k_cvt(const float* __restrict__ x,
                                             const float* __restrict__ w,
                                             const float* __restrict__ pk,
                                             unsigned short* __restrict__ xb,
                                             unsigned short* __restrict__ wt,
                                             unsigned short* __restrict__ pkt){
  __shared__ float tile[64][65];
  const int bid = blockIdx.x;
  if (bid < 2048){
    const int n4 = TKN*1024/4;
    for (int idx = bid*256 + threadIdx.x; idx < n4; idx += 2048*256){
      float4 v = reinterpret_cast<const float4*>(x)[idx];
      ushort4 o;
      o.x = f2bf(v.x); o.y = f2bf(v.y); o.z = f2bf(v.z); o.w = f2bf(v.w);
      reinterpret_cast<ushort4*>(xb)[idx] = o;
    }
  } else if (bid < 2816){
    const int b2 = bid - 2048;
    const int n0 = (b2 % 48)*64, k0 = (b2 / 48)*64;
    const int tn = threadIdx.x & 63, t4 = threadIdx.x >> 6;
    for (int kk = t4; kk < 64; kk += 4)
      tile[kk][tn] = w[(k0+kk)*N3 + n0 + tn];
    __syncthreads();
    for (int nn = t4; nn < 64; nn += 4)
      wt[(n0+nn)*1024 + k0 + tn] = f2bf(tile[tn][nn]);
  } else {
    int i = (bid - 2816)*256 + threadIdx.x;
    int h = i >> 12, e = (i >> 6) & 63, d = i & 63;
    pkt[i] = f2bf(pk[(h<<12) + (d<<6) + e] * 1024.0f);
  }
}

// ---------------- QKV GEMM: 128x128, BK=32, triple-buffer, counted vmcnt ----------------
__global__ __launch_bounds__(256, 3) void k_gemm(const unsigned short* __restrict__ A,
                                                 const unsigned short* __restrict__ Bt,
                                                 unsigned short* __restrict__ qb,
                                                 unsigned short* __restrict__ kb,
                                                 unsigned short* __restrict__ vtb){
  __shared__ unsigned short sm[24576];            // 48KB: A bufs 3x8KB | B bufs 3x8KB
  char* smb = (char*)sm;
  const int tid = threadIdx.x;
  const int lane = tid & 63, wid = tid >> 6;
  const int wm = wid >> 1, wn = wid & 1;
  const int n15 = lane & 15, l4 = lane >> 4;
  const int m0 = blockIdx.y * 128;
  const int n0 = blockIdx.x * 128;

  f32x4 acc[4][4] = {};

  // staging: tile kt (128 rows x 32 k) -> buf b. 512 slots of 16B per matrix, 2/thread.
  const int sr0 = tid >> 2,        sq0 = (tid & 3) ^ (sr0 & 3);
  const int sr1 = (tid + 256) >> 2, sq1 = (tid & 3) ^ (sr1 & 3);
  #define STAGE(kt, b) do {                                                            \
    g2lds16(A  + (long)(m0 + sr0)*1024 + (kt)*32 + sq0*8, smb + (b)*8192 + tid*16);    \
    g2lds16(A  + (long)(m0 + sr1)*1024 + (kt)*32 + sq1*8, smb + (b)*8192 + 4096 + tid*16); \
    g2lds16(Bt + (long)(n0 + sr0)*1024 + (kt)*32 + sq0*8, smb + 24576 + (b)*8192 + tid*16); \
    g2lds16(Bt + (long)(n0 + sr1)*1024 + (kt)*32 + sq1*8, smb + 24576 + (b)*8192 + 4096 + tid*16); \
  } while(0)

  STAGE(0, 0);
  STAGE(1, 1);
  asm volatile("s_waitcnt vmcnt(4)" ::: "memory");
  __builtin_amdgcn_s_barrier();

  int cur = 0;
  for (int t = 0; t < 32; ++t){
    int nb = cur + 2; if (nb >= 3) nb -= 3;
    if (t < 30) STAGE(t + 2, nb);
    const char* ab = smb + cur*8192;
    const char* bb = smb + 24576 + cur*8192;
    short8 a[4], b[4];
    #pragma unroll
    for (int i = 0; i < 4; ++i){
      int ra = wm*64 + i*16 + n15;
      a[i] = *(const short8*)(ab + ra*64 + ((l4 ^ (ra & 3)) << 4));
      int rb = wn*64 + i*16 + n15;
      b[i] = *(const short8*)(bb + rb*64 + ((l4 ^ (rb & 3)) << 4));
    }
    __builtin_amdgcn_s_setprio(1);
    #pragma unroll
    for (int i = 0; i < 4; ++i)
      #pragma unroll
      for (int j = 0; j < 4; ++j)
        acc[i][j] = __builtin_amdgcn_mfma_f32_16x16x32_bf16(a[i], b[j], acc[i][j], 0, 0, 0);
    __builtin_amdgcn_s_setprio(0);
    if (t < 30) asm volatile("s_waitcnt vmcnt(4)" ::: "memory");
    else        asm volatile("s_waitcnt vmcnt(0)" ::: "memory");
    __builtin_amdgcn_s_barrier();
    cur = cur + 1; if (cur == 3) cur = 0;
  }
  #undef STAGE

  // conflict-free per-wave epilogue: 8KB scratch [64 rows][128B], XOR-swizzled
  const int bb2 = m0 >> 10;
  const int which = n0 >> 10;                     // 0=q 1=k 2=v
  const int cw = (n0 & 1023) + wn*64;
  const int h = cw >> 6;                          // wave's 64 cols = one head
  const long bh = (long)(bb2*16 + h);
  const int trow0 = (m0 & 1023) + wm*64;
  char* W = smb + wid*8192;

  if (which < 2){                                 // q,k row-major [b][h][t][64]
    unsigned short* dst = which ? kb : qb;
    #pragma unroll
    for (int mi = 0; mi < 4; ++mi)
      #pragma unroll
      for (int nf = 0; nf < 4; ++nf)
        #pragma unroll
        for (int r = 0; r < 4; ++r){
          int row = mi*16 + l4*4 + r;
          int colb = (nf*32 + 2*n15) ^ ((row & 7) << 4);
          *(unsigned short*)(W + row*128 + colb) = f2bf(acc[mi][nf][r]);
        }
    asm volatile("s_waitcnt lgkmcnt(0)" ::: "memory");
    #pragma unroll
    for (int hh = 0; hh < 2; ++hh)
      #pragma unroll
      for (int c2 = 0; c2 < 4; ++c2){
        int row = hh*32 + (lane >> 1);
        int off = ((lane & 1)*64 + c2*16) ^ ((row & 7) << 4);
        uint4 v = *(const uint4*)(W + row*128 + off);
        int dcol = (lane & 1)*32 + c2*8;
        *(uint4*)(&dst[(bh*1024 + trow0 + row)*64 + dcol]) = v;
      }
  } else {                                        // v transposed [b][h][d][t]
    #pragma unroll
    for (int mi = 0; mi < 4; ++mi)
      #pragma unroll
      for (int nf = 0; nf < 4; ++nf)
        #pragma unroll
        for (int r = 0; r < 4; ++r){
          int dl = nf*16 + n15;
          int row = mi*16 + l4*4 + r;
          int colb = (2*row) ^ ((dl & 7) << 4);
          *(unsigned short*)(W + dl*128 + colb) = f2bf(acc[mi][nf][r]);
        }
    asm volatile("s_waitcnt lgkmcnt(0)" ::: "memory");
    #pragma unroll
    for (int hh = 0; hh < 2; ++hh)
      #pragma unroll
      for (int c2 = 0; c2 < 4; ++c2){
        int dl = hh*32 + (lane >> 1);
        int off = ((lane & 1)*64 + c2*16) ^ ((dl & 7) << 4);
        uint4 v = *(const uint4*)(W + dl*128 + off);
        int tcol = (lane & 1)*32 + c2*8;
        *(uint4*)(&vtb[(bh*64 + dl)*1024 + trow0 + tcol]) = v;
      }
  }
}

// ---------------- attention: paired q-tiles, double-buffered K/V ----------------
__global__ __launch_bounds__(256) void k_attn(const unsigned short* __restrict__ qb,
                                              const unsigned short* __restrict__ kb,
                                              const unsigned short* __restrict__ vtb,
                                              const unsigned short* __restrict__ pkt,
                                              unsigned short* __restrict__ rb,
                                              float* __restrict__ gnp){
  __shared__ unsigned short Qs[8192];
  __shared__ unsigned short Kd[2][4096];
  __shared__ unsigned short Vd[2][4096];
  __shared__ unsigned short Ps[8192];
  __shared__ float gred[2][4];
  const int qpair = blockIdx.x;
  const int bh = blockIdx.y;
  const int h = bh & 15;
  const int tid = threadIdx.x;
  const int lane = tid & 63, wid = tid >> 6;
  const int n15 = lane & 15, l4 = lane >> 4;
  const unsigned short* qp = qb + (long)bh*65536;
  const unsigned short* kp = kb + (long)bh*65536;
  const unsigned short* vp = vtb + (long)bh*65536;
  const float lg = log2f(1.0f - exp2f(-5.0f - (float)h));
  const int srow = tid >> 3, schunk = tid & 7;

  float cexp[4];
  #pragma unroll
  for (int nf = 0; nf < 4; ++nf)
    cexp[nf] = exp2f(-lg * (float)(nf*16 + n15));

  float gs = 0.f, gq = 0.f;
  unsigned short* rp = rb + (long)bh*65536;

  for (int p = 0; p < 2; ++p){
    const int qt = p ? (7 - qpair) : qpair;
    const int t0 = qt * 128;
    for (int c = 0; c < 4; ++c){
      int r = c*32 + srow;
      int src = schunk ^ (r & 7);
      g2lds16(qp + (long)(t0 + r)*64 + src*8, (char*)Qs + c*4096 + tid*16);
    }
    for (int c = 0; c < 2; ++c){
      int r = c*32 + srow;
      int src = schunk ^ (r & 7);
      g2lds16(pkt + (long)(h*64 + r)*64 + src*8, (char*)Ps + c*4096 + tid*16);
      g2lds16(kp + (long)r*64 + src*8, (char*)Kd[0] + c*4096 + tid*16);
      g2lds16(vp + (long)r*1024 + src*8, (char*)Vd[0] + c*4096 + tid*16);
    }
    asm volatile("s_waitcnt vmcnt(0)" ::: "memory");
    __syncthreads();

    short8 aq[2][2];
    #pragma unroll
    for (int mf = 0; mf < 2; ++mf)
      #pragma unroll
      for (int kk = 0; kk < 2; ++kk){
        int r = wid*32 + mf*16 + n15;
        int sl = (kk*4 + l4) ^ (r & 7);
        aq[mf][kk] = *reinterpret_cast<const short8*>((const char*)Qs + r*128 + sl*16);
      }

    f32x4 o[2][4] = {};
    #pragma unroll
    for (int kk = 0; kk < 2; ++kk){
      short8 bpk[4];
      #pragma unroll
      for (int nf = 0; nf < 4; ++nf){
        int r = nf*16 + n15;
        int sl = (kk*4 + l4) ^ (r & 7);
        bpk[nf] = *reinterpret_cast<const short8*>((const char*)Ps + r*128 + sl*16);
      }
      #pragma unroll
      for (int mf = 0; mf < 2; ++mf)
        #pragma unroll
        for (int nf = 0; nf < 4; ++nf)
          o[mf][nf] = __builtin_amdgcn_mfma_f32_16x16x32_bf16(aq[mf][kk], bpk[nf], o[mf][nf], 0,0,0);
    }
    __syncthreads();

    const int jmax = 2*qt + 1;
    int cur = 0;
    for (int j = 0; j <= jmax; ++j){
      const int kv0 = j*64;
      if (j < jmax){
        const int kvn = kv0 + 64;
        for (int c = 0; c < 2; ++c){
          int r = c*32 + srow;
          int src = schunk ^ (r & 7);
          g2lds16(kp + (long)(kvn + r)*64 + src*8, (char*)Kd[cur^1] + c*4096 + tid*16);
          g2lds16(vp + (long)r*1024 + kvn + src*8, (char*)Vd[cur^1] + c*4096 + tid*16);
        }
      }
      f32x4 s[2][4] = {};
      #pragma unroll
      for (int kk = 0; kk < 2; ++kk){
        short8 bk[4];
        #pragma unroll
        for (int nf = 0; nf < 4; ++nf){
          int r = nf*16 + n15;
          int sl = (kk*4 + l4) ^ (r & 7);
          bk[nf] = *reinterpret_cast<const short8*>((const char*)Kd[cur] + r*128 + sl*16);
        }
        #pragma unroll
        for (int mf = 0; mf < 2; ++mf)
          #pragma unroll
          for (int nf = 0; nf < 4; ++nf)
            s[mf][nf] = __builtin_amdgcn_mfma_f32_16x16x32_bf16(aq[mf][kk], bk[nf], s[mf][nf], 0,0,0);
      }
      float rowf[2][4];
      #pragma unroll
      for (int mf = 0; mf < 2; ++mf){
        int mB = wid*32 + mf*16 + l4*4;
        #pragma unroll
        for (int r = 0; r < 4; ++r)
          rowf[mf][r] = exp2f(lg * (float)(t0 + mB + r - kv0));
      }
      if (kv0 >= t0){
        #pragma unroll
        for (int mf = 0; mf < 2; ++mf){
          int mB = wid*32 + mf*16 + l4*4;
          #pragma unroll
          for (int nf = 0; nf < 4; ++nf){
            int tj = kv0 + nf*16 + n15;
            int n = nf*16 + n15;
            #pragma unroll
            for (int r = 0; r < 4; ++r){
              int ti = t0 + mB + r;
              float val = (ti >= tj) ? s[mf][nf][r] * (rowf[mf][r] * cexp[nf]) : 0.0f;
              int byte = ((mB + r)*128 + n*2) ^ (((mB + r) & 7) << 4);
              *(unsigned short*)((char*)Ps + byte) = f2bf(val);
            }
          }
        }
      } else {
        #pragma unroll
        for (int mf = 0; mf < 2; ++mf){
          int mB = wid*32 + mf*16 + l4*4;
          #pragma unroll
          for (int nf = 0; nf < 4; ++nf){
            int n = nf*16 + n15;
            #pragma unroll
            for (int r = 0; r < 4; ++r){
              float val = s[mf][nf][r] * (rowf[mf][r] * cexp[nf]);
              int byte = ((mB + r)*128 + n*2) ^ (((mB + r) & 7) << 4);
              *(unsigned short*)((char*)Ps + byte) = f2bf(val);
            }
          }
        }
      }
      #pragma unroll
      for (int kk = 0; kk < 2; ++kk){
        short8 ap[2], bv[4];
        #pragma unroll
        for (int mf = 0; mf < 2; ++mf){
          int r = wid*32 + mf*16 + n15;
          int sl = (kk*4 + l4) ^ (r & 7);
          ap[mf] = *reinterpret_cast<const short8*>((const char*)Ps + r*128 + sl*16);
        }
        #pragma unroll
        for (int nf = 0; nf < 4; ++nf){
          int r = nf*16 + n15;
          int sl = (kk*4 + l4) ^ (r & 7);
          bv[nf] = *reinterpret_cast<const short8*>((const char*)Vd[cur] + r*128 + sl*16);
        }
        #pragma unroll
        for (int mf = 0; mf < 2; ++mf)
          #pragma unroll
          for (int nf = 0; nf < 4; ++nf)
            o[mf][nf] = __builtin_amdgcn_mfma_f32_16x16x32_bf16(ap[mf], bv[nf], o[mf][nf], 0,0,0);
      }
      asm volatile("s_waitcnt vmcnt(0)" ::: "memory");
      __syncthreads();
      cur ^= 1;
    }
    #pragma unroll
    for (int mf = 0; mf < 2; ++mf)
      #pragma unroll
      for (int nf = 0; nf < 4; ++nf)
        #pragma unroll
        for (int r = 0; r < 4; ++r){
          int t = t0 + wid*32 + mf*16 + l4*4 + r;
          int d = nf*16 + n15;
          float v = o[mf][nf][r];
          rp[t*64 + d] = f2bf(v);
          gs += v; gq += v*v;
        }
  }
  #pragma unroll
  for (int off = 32; off > 0; off >>= 1){
    gs += __shfl_down(gs, off);
    gq += __shfl_down(gq, off);
  }
  if (lane == 0){ gred[0][wid] = gs; gred[1][wid] = gq; }
  __syncthreads();
  if (tid == 0){
    gnp[(bh*4 + qpair)*2]   = gred[0][0]+gred[0][1]+gred[0][2]+gred[0][3];
    gnp[(bh*4 + qpair)*2+1] = gred[1][0]+gred[1][1]+gred[1][2]+gred[1][3];
  }
}

// ---------------- K^T V partials (LDS-transpose vector-FMA) ----------------
__global__ __launch_bounds__(256) void k_kvpart(const unsigned short* __restrict__ kb,
                                                const unsigned short* __restrict__ vtb,
                                                float* __restrict__ part){
  __shared__ unsigned short Kt[64*64];            // [t][d]
  __shared__ unsigned int   Vt32[64*33];          // [e][t] padded rows (66 ushorts)
  const int tc = blockIdx.x, bh = blockIdx.y;
  const int tid = threadIdx.x;
  const int d0 = (tid >> 4) << 2;
  const int e0 = (tid & 15) << 2;
  const unsigned short* kp = kb + (long)bh*65536;
  const unsigned short* vp = vtb + (long)bh*65536;
  float acc[4][4] = {{0.f}};
  for (int tt = 0; tt < 4; ++tt){
    const int tb = tc*256 + tt*64;
    __syncthreads();
    {
      int rr0 = tid >> 3, off = (tid & 7) * 8;
      for (int c = 0; c < 2; ++c){
        int r = c*32 + rr0;
        *reinterpret_cast<uint4*>(&Kt[r*64 + off]) =
            *reinterpret_cast<const uint4*>(&kp[(long)(tb + r)*64 + off]);
        uint4 vv = *reinterpret_cast<const uint4*>(&vp[(long)r*1024 + tb + off]);
        unsigned int* dv = &Vt32[r*33 + (off >> 1)];
        dv[0] = vv.x; dv[1] = vv.y; dv[2] = vv.z; dv[3] = vv.w;
      }
    }
    __syncthreads();
    const unsigned short* Vt = (const unsigned short*)Vt32;
    for (int t = 0; t < 64; ++t){
      float kv[4], vv[4];
      #pragma unroll
      for (int i = 0; i < 4; ++i) kv[i] = bf2f(Kt[t*64 + d0 + i]);
      #pragma unroll
      for (int i = 0; i < 4; ++i) vv[i] = bf2f(Vt[(e0 + i)*66 + t]);
      #pragma unroll
      for (int i = 0; i < 4; ++i)
        #pragma unroll
        for (int j = 0; j < 4; ++j) acc[i][j] += kv[i]*vv[j];
    }
  }
  float* pp = part + ((long)(tc*128 + bh) << 12);
  for (int i = 0; i < 4; ++i)
    for (int j = 0; j < 4; ++j)
      pp[(d0+i)*64 + e0 + j] = acc[i][j];
}

// kvfin + GroupNorm stage-2 fused (block 0, first 8 threads do mu/sigma)
__global__ __launch_bounds__(256) void k_kvfin(const float* __restrict__ part,
                                               const float* __restrict__ pk,
                                               float* __restrict__ okv,
                                               const float* __restrict__ gnp,
                                               float* __restrict__ musig){
  if (blockIdx.x == 0 && threadIdx.x < 8){
    int b = threadIdx.x;
    float S = 0.f, Q = 0.f;
    for (int g = 0; g < 64; ++g){ S += gnp[b*128 + g*2]; Q += gnp[b*128 + g*2 + 1]; }
    float mu  = S * (1.0f/1048576.0f);
    float var = Q * (1.0f/1048576.0f) - mu*mu;
    musig[b*2]   = mu;
    musig[b*2+1] = rsqrtf(var + 1e-5f);
  }
  int i = blockIdx.x*256 + threadIdx.x;           // 65536
  int h = i >> 12;
  float acc = 0.f;
  for (int tc = 0; tc < 4; ++tc)
    for (int b = 0; b < 8; ++b)
      acc += part[((long)(tc*128 + b*16 + h) << 12) + (i & 4095)];
  float gamma = 1.0f - exp2f(-5.0f - (float)h);
  okv[i] = gamma * pk[i] + acc * 0.125f;
}

__global__ __launch_bounds__(256) void k_gnnorm(const unsigned short* __restrict__ rbuf,
                                                const float* __restrict__ musig,
                                                const float* __restrict__ gw,
                                                const float* __restrict__ gb,
                                                float* __restrict__ out){
  const int n8 = TKN*1024/8;
  for (int idx = blockIdx.x*256 + threadIdx.x; idx < n8; idx += gridDim.x*256){
    int o = idx*8;
    int c = o & 1023;
    int t = (o >> 10) & 1023;
    int b = o >> 20;
    int h = c >> 6, d = c & 63;
    short8 v = *reinterpret_cast<const short8*>(rbuf + ((long)(b*16 + h) << 16) + t*64 + d);
    float rs = musig[b*2+1];
    float a = gw[h]*rs, b2 = gb[h] - musig[b*2]*a;
    float4 o0, o1;
    o0.x = bf2f((unsigned short)v[0])*a + b2;
    o0.y = bf2f((unsigned short)v[1])*a + b2;
    o0.z = bf2f((unsigned short)v[2])*a + b2;
    o0.w = bf2f((unsigned short)v[3])*a + b2;
    o1.x = bf2f((unsigned short)v[4])*a + b2;
    o1.y = bf2f((unsigned short)v[5])*a + b2;
    o1.z = bf2f((unsigned short)v[6])*a + b2;
    o1.w = bf2f((unsigned short)v[7])*a + b2;
    *reinterpret_cast<float4*>(out + o)     = o0;
    *reinterpret_cast<float4*>(out + o + 4) = o1;
  }
}

extern "C" void kernel_launch(void* const* d_in, const int* in_sizes, int n_in,
                              void* d_out, int out_size, void* d_ws, size_t ws_size,
                              hipStream_t stream){
  const float* x  = (const float*)d_in[0];
  const float* pk = (const float*)d_in[1];
  const float* w  = (const float*)d_in[2];
  const float* gw = (const float*)d_in[3];
  const float* gb = (const float*)d_in[4];
  float* out = (float*)d_out;
  char* ws = (char*)d_ws;

  unsigned short* Xb  = (unsigned short*)(ws);                 // 16 MB (aliased by KVp later)
  unsigned short* WTb = (unsigned short*)(ws + 16777216);      //  6 MB
  unsigned short* Qb  = (unsigned short*)(ws + 23068672);      // 16 MB
  unsigned short* Kb  = (unsigned short*)(ws + 39845888);      // 16 MB
  unsigned short* VTb = (unsigned short*)(ws + 56623104);      // 16 MB
  unsigned short* PKt = (unsigned short*)(ws + 73400320);      // 128 KB
  unsigned short* Rb  = (unsigned short*)(ws + 73531392);      // 16 MB (bf16)
  float* KVp = (float*)(ws);                                   // 8 MB, aliases Xb (dead after gemm)
  float* GNp = (float*)(ws + 90308608);                        // 4 KB
  float* MuS = (float*)(ws + 90312704);                        // 64 B

  k_cvt    <<<dim3(3072),    dim3(256), 0, stream>>>(x, w, pk, Xb, WTb, PKt);
  k_gemm   <<<dim3(24, 64),  dim3(256), 0, stream>>>(Xb, WTb, Qb, Kb, VTb);
  k_attn   <<<dim3(4, 128),  dim3(256), 0, stream>>>(Qb, Kb, VTb, PKt, Rb, GNp);
  k_kvpart <<<dim3(4, 128),  dim3(256), 0, stream>>>(Kb, VTb, KVp);
  k_kvfin  <<<dim3(256),     dim3(256), 0, stream>>>(KVp, pk, out + 8388608, GNp, MuS);
  k_gnnorm <<<dim3(1024),    dim3(256), 0, stream>>>(Rb, MuS, gw, gb, out);
}

// Round 6
// 163.591 us; speedup vs baseline: 1.4140x; 1.1220x over previous
//
#include <hip/hip_runtime.h>

// ChunkwiseRetention: B=8 T=1024 C=1024 NH=16 HD=64
// out[b,t,h*64+d] = GN_b(r)*w[h]+bias[h],  r = (QK^T ∘ decay)V + 1024*Q@past_kv
// current_kv[h] = gamma_h*past_kv[h] + mean_b(K^T V)

#define TKN 8192
#define N3  3072

typedef short short8 __attribute__((ext_vector_type(8)));
typedef float f32x4 __attribute__((ext_vector_type(4)));

static __device__ __forceinline__ unsigned short f2bf(float f){
  unsigned int u = __float_as_uint(f);
  u += 0x7FFFu + ((u >> 16) & 1u);
  return (unsigned short)(u >> 16);
}
static __device__ __forceinline__ float bf2f(unsigned short s){
  return __uint_as_float(((unsigned int)s) << 16);
}
static __device__ __forceinline__ void g2lds16(const void* g, void* l){
  __builtin_amdgcn_global_load_lds(
      (const __attribute__((address_space(1))) unsigned int*)g,
      (__attribute__((address_space(3))) unsigned int*)l, 16, 0, 0);
}

// ---------------- merged conversions ----------------
__global__ __launch_bounds__(256) void k_cvt(const float* __restrict__ x,
                                             const float* __restrict__ w,
                                             const float* __restrict__ pk,
                                             unsigned short* __restrict__ xb,
                                             unsigned short* __restrict__ wt,
                                             unsigned short* __restrict__ pkt){
  __shared__ float tile[64][65];
  const int bid = blockIdx.x;
  if (bid < 2048){
    const int n4 = TKN*1024/4;
    for (int idx = bid*256 + threadIdx.x; idx < n4; idx += 2048*256){
      float4 v = reinterpret_cast<const float4*>(x)[idx];
      ushort4 o;
      o.x = f2bf(v.x); o.y = f2bf(v.y); o.z = f2bf(v.z); o.w = f2bf(v.w);
      reinterpret_cast<ushort4*>(xb)[idx] = o;
    }
  } else if (bid < 2816){
    const int b2 = bid - 2048;
    const int n0 = (b2 % 48)*64, k0 = (b2 / 48)*64;
    const int tn = threadIdx.x & 63, t4 = threadIdx.x >> 6;
    for (int kk = t4; kk < 64; kk += 4)
      tile[kk][tn] = w[(k0+kk)*N3 + n0 + tn];
    __syncthreads();
    for (int nn = t4; nn < 64; nn += 4)
      wt[(n0+nn)*1024 + k0 + tn] = f2bf(tile[tn][nn]);
  } else {
    int i = (bid - 2816)*256 + threadIdx.x;
    int h = i >> 12, e = (i >> 6) & 63, d = i & 63;
    pkt[i] = f2bf(pk[(h<<12) + (d<<6) + e] * 1024.0f);
  }
}

// ---------------- QKV GEMM: 128x128, BK=32, triple-buffer, counted vmcnt ----------------
// LDS layout fix: row r stored at line swap01(r); chunk c at slot c ^ ((r>>2)&3).
// Per 16-lane group granule = (n15&2)*2 + (l4 ^ (n15>>2)): 8 granules x 2 lanes (free).
__global__ __launch_bounds__(256, 3) void k_gemm(const unsigned short* __restrict__ A,
                                                 const unsigned short* __restrict__ Bt,
                                                 unsigned short* __restrict__ qb,
                                                 unsigned short* __restrict__ kb,
                                                 unsigned short* __restrict__ vtb){
  __shared__ unsigned short sm[24576];            // 48KB: A bufs 3x8KB | B bufs 3x8KB
  char* smb = (char*)sm;
  const int tid = threadIdx.x;
  const int lane = tid & 63, wid = tid >> 6;
  const int wm = wid >> 1, wn = wid & 1;
  const int n15 = lane & 15, l4 = lane >> 4;
  const int m0 = blockIdx.y * 128;
  const int n0 = blockIdx.x * 128;

  f32x4 acc[4][4] = {};

  // staging: dest line l0 = tid>>2 hosts row r0 = swap01(l0); slot tid&3 holds chunk c.
  const int l0 = tid >> 2;
  const int r0 = (l0 & ~3) | ((l0 & 1) << 1) | ((l0 >> 1) & 1);
  const int c0 = (((tid & 3) ^ ((tid >> 4) & 3)) << 3);   // chunk*8 elems
  #define STAGE(kt, b) do {                                                              \
    g2lds16(A  + (long)(m0 + r0)*1024      + (kt)*32 + c0, smb + (b)*8192 + tid*16);     \
    g2lds16(A  + (long)(m0 + 64 + r0)*1024 + (kt)*32 + c0, smb + (b)*8192 + 4096 + tid*16); \
    g2lds16(Bt + (long)(n0 + r0)*1024      + (kt)*32 + c0, smb + 24576 + (b)*8192 + tid*16); \
    g2lds16(Bt + (long)(n0 + 64 + r0)*1024 + (kt)*32 + c0, smb + 24576 + (b)*8192 + 4096 + tid*16); \
  } while(0)

  STAGE(0, 0);
  STAGE(1, 1);
  asm volatile("s_waitcnt vmcnt(4)" ::: "memory");
  __builtin_amdgcn_s_barrier();

  const int slb = (l4 ^ ((n15 >> 2) & 3)) << 4;   // slot byte (row-invariant)
  int cur = 0;
  for (int t = 0; t < 32; ++t){
    int nb = cur + 2; if (nb >= 3) nb -= 3;
    if (t < 30) STAGE(t + 2, nb);
    const char* ab = smb + cur*8192;
    const char* bb = smb + 24576 + cur*8192;
    short8 a[4], b[4];
    #pragma unroll
    for (int i = 0; i < 4; ++i){
      int ra = wm*64 + i*16 + n15;
      int rs = (ra & ~3) | ((ra & 1) << 1) | ((ra >> 1) & 1);
      a[i] = *(const short8*)(ab + rs*64 + slb);
      int rb = wn*64 + i*16 + n15;
      int rbs = (rb & ~3) | ((rb & 1) << 1) | ((rb >> 1) & 1);
      b[i] = *(const short8*)(bb + rbs*64 + slb);
    }
    __builtin_amdgcn_s_setprio(1);
    #pragma unroll
    for (int i = 0; i < 4; ++i)
      #pragma unroll
      for (int j = 0; j < 4; ++j)
        acc[i][j] = __builtin_amdgcn_mfma_f32_16x16x32_bf16(a[i], b[j], acc[i][j], 0, 0, 0);
    __builtin_amdgcn_s_setprio(0);
    if (t < 30) asm volatile("s_waitcnt vmcnt(4)" ::: "memory");
    else        asm volatile("s_waitcnt vmcnt(0)" ::: "memory");
    __builtin_amdgcn_s_barrier();
    cur = cur + 1; if (cur == 3) cur = 0;
  }
  #undef STAGE

  // conflict-free per-wave epilogue: 8KB scratch [64 rows][128B], XOR-swizzled
  const int bb2 = m0 >> 10;
  const int which = n0 >> 10;                     // 0=q 1=k 2=v
  const int cw = (n0 & 1023) + wn*64;
  const int h = cw >> 6;
  const long bh = (long)(bb2*16 + h);
  const int trow0 = (m0 & 1023) + wm*64;
  char* W = smb + wid*8192;

  if (which < 2){                                 // q,k row-major [b][h][t][64]
    unsigned short* dst = which ? kb : qb;
    #pragma unroll
    for (int mi = 0; mi < 4; ++mi)
      #pragma unroll
      for (int nf = 0; nf < 4; ++nf)
        #pragma unroll
        for (int r = 0; r < 4; ++r){
          int row = mi*16 + l4*4 + r;
          int colb = (nf*32 + 2*n15) ^ ((row & 7) << 4);
          *(unsigned short*)(W + row*128 + colb) = f2bf(acc[mi][nf][r]);
        }
    asm volatile("s_waitcnt lgkmcnt(0)" ::: "memory");
    #pragma unroll
    for (int hh = 0; hh < 2; ++hh)
      #pragma unroll
      for (int c2 = 0; c2 < 4; ++c2){
        int row = hh*32 + (lane >> 1);
        int off = ((lane & 1)*64 + c2*16) ^ ((row & 7) << 4);
        uint4 v = *(const uint4*)(W + row*128 + off);
        int dcol = (lane & 1)*32 + c2*8;
        *(uint4*)(&dst[(bh*1024 + trow0 + row)*64 + dcol]) = v;
      }
  } else {                                        // v transposed [b][h][d][t]
    #pragma unroll
    for (int mi = 0; mi < 4; ++mi)
      #pragma unroll
      for (int nf = 0; nf < 4; ++nf)
        #pragma unroll
        for (int r = 0; r < 4; ++r){
          int dl = nf*16 + n15;
          int row = mi*16 + l4*4 + r;
          int colb = (2*row) ^ ((dl & 7) << 4);
          *(unsigned short*)(W + dl*128 + colb) = f2bf(acc[mi][nf][r]);
        }
    asm volatile("s_waitcnt lgkmcnt(0)" ::: "memory");
    #pragma unroll
    for (int hh = 0; hh < 2; ++hh)
      #pragma unroll
      for (int c2 = 0; c2 < 4; ++c2){
        int dl = hh*32 + (lane >> 1);
        int off = ((lane & 1)*64 + c2*16) ^ ((dl & 7) << 4);
        uint4 v = *(const uint4*)(W + dl*128 + off);
        int tcol = (lane & 1)*32 + c2*8;
        *(uint4*)(&vtb[(bh*64 + dl)*1024 + trow0 + tcol]) = v;
      }
  }
}

// ---------------- attention: swapped QK^T, packed P-writes, coalesced R ----------------
__global__ __launch_bounds__(256) void k_attn(const unsigned short* __restrict__ qb,
                                              const unsigned short* __restrict__ kb,
                                              const unsigned short* __restrict__ vtb,
                                              const unsigned short* __restrict__ pkt,
                                              unsigned short* __restrict__ rb,
                                              float* __restrict__ gnp){
  __shared__ unsigned short Qs[8192];
  __shared__ unsigned short Kd[2][4096];
  __shared__ unsigned short Vd[2][4096];
  __shared__ unsigned short Ps[8192];
  __shared__ float gred[2][4];
  const int qpair = blockIdx.x;
  const int bh = blockIdx.y;
  const int h = bh & 15;
  const int tid = threadIdx.x;
  const int lane = tid & 63, wid = tid >> 6;
  const int n15 = lane & 15, l4 = lane >> 4;
  const unsigned short* qp = qb + (long)bh*65536;
  const unsigned short* kp = kb + (long)bh*65536;
  const unsigned short* vp = vtb + (long)bh*65536;
  const float lg = log2f(1.0f - exp2f(-5.0f - (float)h));
  const int srow = tid >> 3, schunk = tid & 7;

  // gamma^{-(kv within tile)}: kv = i*16 + l4*4 + r
  float kvE[4][4];
  #pragma unroll
  for (int i = 0; i < 4; ++i)
    #pragma unroll
    for (int r = 0; r < 4; ++r)
      kvE[i][r] = exp2f(-lg * (float)(i*16 + l4*4 + r));

  float gs = 0.f, gq = 0.f;
  unsigned short* rp = rb + (long)bh*65536;

  for (int p = 0; p < 2; ++p){
    const int qt = p ? (7 - qpair) : qpair;
    const int t0 = qt * 128;
    for (int c = 0; c < 4; ++c){
      int r = c*32 + srow;
      int src = schunk ^ (r & 7);
      g2lds16(qp + (long)(t0 + r)*64 + src*8, (char*)Qs + c*4096 + tid*16);
    }
    for (int c = 0; c < 2; ++c){
      int r = c*32 + srow;
      int src = schunk ^ (r & 7);
      g2lds16(pkt + (long)(h*64 + r)*64 + src*8, (char*)Ps + c*4096 + tid*16);
      g2lds16(kp + (long)r*64 + src*8, (char*)Kd[0] + c*4096 + tid*16);
      g2lds16(vp + (long)r*1024 + src*8, (char*)Vd[0] + c*4096 + tid*16);
    }
    asm volatile("s_waitcnt vmcnt(0)" ::: "memory");
    __syncthreads();

    short8 aq[2][2];
    #pragma unroll
    for (int mf = 0; mf < 2; ++mf)
      #pragma unroll
      for (int kk = 0; kk < 2; ++kk){
        int r = wid*32 + mf*16 + n15;
        int sl = (kk*4 + l4) ^ (r & 7);
        aq[mf][kk] = *reinterpret_cast<const short8*>((const char*)Qs + r*128 + sl*16);
      }

    f32x4 o[2][4] = {};                           // cross = Q @ (pk^T*1024), [t][e]
    #pragma unroll
    for (int kk = 0; kk < 2; ++kk){
      short8 bpk[4];
      #pragma unroll
      for (int nf = 0; nf < 4; ++nf){
        int r = nf*16 + n15;
        int sl = (kk*4 + l4) ^ (r & 7);
        bpk[nf] = *reinterpret_cast<const short8*>((const char*)Ps + r*128 + sl*16);
      }
      #pragma unroll
      for (int mf = 0; mf < 2; ++mf)
        #pragma unroll
        for (int nf = 0; nf < 4; ++nf)
          o[mf][nf] = __builtin_amdgcn_mfma_f32_16x16x32_bf16(aq[mf][kk], bpk[nf], o[mf][nf], 0,0,0);
    }
    __syncthreads();                              // Ps free for P

    const int jmax = 2*qt + 1;
    int cur = 0;
    for (int j = 0; j <= jmax; ++j){
      const int kv0 = j*64;
      if (j < jmax){
        const int kvn = kv0 + 64;
        for (int c = 0; c < 2; ++c){
          int r = c*32 + srow;
          int src = schunk ^ (r & 7);
          g2lds16(kp + (long)(kvn + r)*64 + src*8, (char*)Kd[cur^1] + c*4096 + tid*16);
          g2lds16(vp + (long)r*1024 + kvn + src*8, (char*)Vd[cur^1] + c*4096 + tid*16);
        }
      }
      const bool active = (kv0 <= t0 + wid*32 + 31);   // wave-uniform
      if (active){
        // S^T = K Q^T : sT[i over kv][mf over t]; lane: t = wid*32+mf*16+n15, kv = i*16+l4*4+r
        f32x4 sT[4][2] = {};
        #pragma unroll
        for (int kk = 0; kk < 2; ++kk){
          short8 bk[4];
          #pragma unroll
          for (int i = 0; i < 4; ++i){
            int r = i*16 + n15;
            int sl = (kk*4 + l4) ^ (r & 7);
            bk[i] = *reinterpret_cast<const short8*>((const char*)Kd[cur] + r*128 + sl*16);
          }
          #pragma unroll
          for (int i = 0; i < 4; ++i)
            #pragma unroll
            for (int mf = 0; mf < 2; ++mf)
              sT[i][mf] = __builtin_amdgcn_mfma_f32_16x16x32_bf16(bk[i], aq[mf][kk], sT[i][mf], 0,0,0);
        }
        // decay + pack 4 kv into b64, write P [t][kv] swizzled
        const bool diag = (kv0 + 63 > t0 + wid*32);
        #pragma unroll
        for (int mf = 0; mf < 2; ++mf){
          const int trow = wid*32 + mf*16 + n15;
          const float rowE = exp2f(lg * (float)(t0 + trow - kv0));
          char* wb = (char*)Ps + trow*128;
          const int swz = (trow & 7) << 4;
          #pragma unroll
          for (int i = 0; i < 4; ++i){
            float v0 = sT[i][mf][0] * (rowE * kvE[i][0]);
            float v1 = sT[i][mf][1] * (rowE * kvE[i][1]);
            float v2 = sT[i][mf][2] * (rowE * kvE[i][2]);
            float v3 = sT[i][mf][3] * (rowE * kvE[i][3]);
            if (diag){
              int dd = (t0 + trow) - (kv0 + i*16 + l4*4);
              if (dd < 0) v0 = 0.f;
              if (dd < 1) v1 = 0.f;
              if (dd < 2) v2 = 0.f;
              if (dd < 3) v3 = 0.f;
            }
            uint2 pw;
            pw.x = (unsigned int)f2bf(v0) | ((unsigned int)f2bf(v1) << 16);
            pw.y = (unsigned int)f2bf(v2) | ((unsigned int)f2bf(v3) << 16);
            *(uint2*)(wb + ((i*32 + l4*8) ^ swz)) = pw;
          }
        }
        // O += P @ V
        #pragma unroll
        for (int kk = 0; kk < 2; ++kk){
          short8 ap[2], bv[4];
          #pragma unroll
          for (int mf = 0; mf < 2; ++mf){
            int r = wid*32 + mf*16 + n15;
            int sl = (kk*4 + l4) ^ (r & 7);
            ap[mf] = *reinterpret_cast<const short8*>((const char*)Ps + r*128 + sl*16);
          }
          #pragma unroll
          for (int nf = 0; nf < 4; ++nf){
            int r = nf*16 + n15;
            int sl = (kk*4 + l4) ^ (r & 7);
            bv[nf] = *reinterpret_cast<const short8*>((const char*)Vd[cur] + r*128 + sl*16);
          }
          #pragma unroll
          for (int mf = 0; mf < 2; ++mf)
            #pragma unroll
            for (int nf = 0; nf < 4; ++nf)
              o[mf][nf] = __builtin_amdgcn_mfma_f32_16x16x32_bf16(ap[mf], bv[nf], o[mf][nf], 0,0,0);
        }
      }
      asm volatile("s_waitcnt vmcnt(0)" ::: "memory");
      __syncthreads();
      cur ^= 1;
    }
    // epilogue: o -> Ps (wave-local, swizzled) -> coalesced global; + GN partials
    #pragma unroll
    for (int mf = 0; mf < 2; ++mf)
      #pragma unroll
      for (int nf = 0; nf < 4; ++nf)
        #pragma unroll
        for (int r = 0; r < 4; ++r){
          int trow = wid*32 + mf*16 + l4*4 + r;
          int d = nf*16 + n15;
          float v = o[mf][nf][r];
          gs += v; gq += v*v;
          *(unsigned short*)((char*)Ps + trow*128 + ((2*d) ^ ((trow & 7) << 4))) = f2bf(v);
        }
    asm volatile("s_waitcnt lgkmcnt(0)" ::: "memory");
    #pragma unroll
    for (int rr = 0; rr < 4; ++rr){
      int row = wid*32 + rr*8 + (lane >> 3);
      int off = (((lane & 7) << 4) ^ ((row & 7) << 4));
      uint4 v = *(const uint4*)((const char*)Ps + row*128 + off);
      *(uint4*)(rp + (long)(t0 + row)*64 + ((lane & 7) << 3)) = v;
    }
    __syncthreads();                              // protect Ps before next p staging
  }
  #pragma unroll
  for (int off = 32; off > 0; off >>= 1){
    gs += __shfl_down(gs, off);
    gq += __shfl_down(gq, off);
  }
  if (lane == 0){ gred[0][wid] = gs; gred[1][wid] = gq; }
  __syncthreads();
  if (tid == 0){
    gnp[(bh*4 + qpair)*2]   = gred[0][0]+gred[0][1]+gred[0][2]+gred[0][3];
    gnp[(bh*4 + qpair)*2+1] = gred[1][0]+gred[1][1]+gred[1][2]+gred[1][3];
  }
}

// ---------------- K^T V partials (LDS-transpose vector-FMA) ----------------
__global__ __launch_bounds__(256) void k_kvpart(const unsigned short* __restrict__ kb,
                                                const unsigned short* __restrict__ vtb,
                                                float* __restrict__ part){
  __shared__ unsigned short Kt[64*64];            // [t][d]
  __shared__ unsigned int   Vt32[64*33];          // [e][t] padded rows (66 ushorts)
  const int tc = blockIdx.x, bh = blockIdx.y;
  const int tid = threadIdx.x;
  const int d0 = (tid >> 4) << 2;
  const int e0 = (tid & 15) << 2;
  const unsigned short* kp = kb + (long)bh*65536;
  const unsigned short* vp = vtb + (long)bh*65536;
  float acc[4][4] = {{0.f}};
  for (int tt = 0; tt < 4; ++tt){
    const int tb = tc*256 + tt*64;
    __syncthreads();
    {
      int rr0 = tid >> 3, off = (tid & 7) * 8;
      for (int c = 0; c < 2; ++c){
        int r = c*32 + rr0;
        *reinterpret_cast<uint4*>(&Kt[r*64 + off]) =
            *reinterpret_cast<const uint4*>(&kp[(long)(tb + r)*64 + off]);
        uint4 vv = *reinterpret_cast<const uint4*>(&vp[(long)r*1024 + tb + off]);
        unsigned int* dv = &Vt32[r*33 + (off >> 1)];
        dv[0] = vv.x; dv[1] = vv.y; dv[2] = vv.z; dv[3] = vv.w;
      }
    }
    __syncthreads();
    const unsigned short* Vt = (const unsigned short*)Vt32;
    for (int t = 0; t < 64; ++t){
      float kv[4], vv[4];
      #pragma unroll
      for (int i = 0; i < 4; ++i) kv[i] = bf2f(Kt[t*64 + d0 + i]);
      #pragma unroll
      for (int i = 0; i < 4; ++i) vv[i] = bf2f(Vt[(e0 + i)*66 + t]);
      #pragma unroll
      for (int i = 0; i < 4; ++i)
        #pragma unroll
        for (int j = 0; j < 4; ++j) acc[i][j] += kv[i]*vv[j];
    }
  }
  float* pp = part + ((long)(tc*128 + bh) << 12);
  for (int i = 0; i < 4; ++i)
    for (int j = 0; j < 4; ++j)
      pp[(d0+i)*64 + e0 + j] = acc[i][j];
}

// kvfin + GroupNorm stage-2 fused
__global__ __launch_bounds__(256) void k_kvfin(const float* __restrict__ part,
                                               const float* __restrict__ pk,
                                               float* __restrict__ okv,
                                               const float* __restrict__ gnp,
                                               float* __restrict__ musig){
  if (blockIdx.x == 0 && threadIdx.x < 8){
    int b = threadIdx.x;
    float S = 0.f, Q = 0.f;
    for (int g = 0; g < 64; ++g){ S += gnp[b*128 + g*2]; Q += gnp[b*128 + g*2 + 1]; }
    float mu  = S * (1.0f/1048576.0f);
    float var = Q * (1.0f/1048576.0f) - mu*mu;
    musig[b*2]   = mu;
    musig[b*2+1] = rsqrtf(var + 1e-5f);
  }
  int i = blockIdx.x*256 + threadIdx.x;           // 65536
  int h = i >> 12;
  float acc = 0.f;
  for (int tc = 0; tc < 4; ++tc)
    for (int b = 0; b < 8; ++b)
      acc += part[((long)(tc*128 + b*16 + h) << 12) + (i & 4095)];
  float gamma = 1.0f - exp2f(-5.0f - (float)h);
  okv[i] = gamma * pk[i] + acc * 0.125f;
}

__global__ __launch_bounds__(256) void k_gnnorm(const unsigned short* __restrict__ rbuf,
                                                const float* __restrict__ musig,
                                                const float* __restrict__ gw,
                                                const float* __restrict__ gb,
                                                float* __restrict__ out){
  const int n8 = TKN*1024/8;
  for (int idx = blockIdx.x*256 + threadIdx.x; idx < n8; idx += gridDim.x*256){
    int o = idx*8;
    int c = o & 1023;
    int t = (o >> 10) & 1023;
    int b = o >> 20;
    int h = c >> 6, d = c & 63;
    short8 v = *reinterpret_cast<const short8*>(rbuf + ((long)(b*16 + h) << 16) + t*64 + d);
    float rs = musig[b*2+1];
    float a = gw[h]*rs, b2 = gb[h] - musig[b*2]*a;
    float4 o0, o1;
    o0.x = bf2f((unsigned short)v[0])*a + b2;
    o0.y = bf2f((unsigned short)v[1])*a + b2;
    o0.z = bf2f((unsigned short)v[2])*a + b2;
    o0.w = bf2f((unsigned short)v[3])*a + b2;
    o1.x = bf2f((unsigned short)v[4])*a + b2;
    o1.y = bf2f((unsigned short)v[5])*a + b2;
    o1.z = bf2f((unsigned short)v[6])*a + b2;
    o1.w = bf2f((unsigned short)v[7])*a + b2;
    *reinterpret_cast<float4*>(out + o)     = o0;
    *reinterpret_cast<float4*>(out + o + 4) = o1;
  }
}

extern "C" void kernel_launch(void* const* d_in, const int* in_sizes, int n_in,
                              void* d_out, int out_size, void* d_ws, size_t ws_size,
                              hipStream_t stream){
  const float* x  = (const float*)d_in[0];
  const float* pk = (const float*)d_in[1];
  const float* w  = (const float*)d_in[2];
  const float* gw = (const float*)d_in[3];
  const float* gb = (const float*)d_in[4];
  float* out = (float*)d_out;
  char* ws = (char*)d_ws;

  unsigned short* Xb  = (unsigned short*)(ws);                 // 16 MB (aliased by KVp later)
  unsigned short* WTb = (unsigned short*)(ws + 16777216);      //  6 MB
  unsigned short* Qb  = (unsigned short*)(ws + 23068672);      // 16 MB
  unsigned short* Kb  = (unsigned short*)(ws + 39845888);      // 16 MB
  unsigned short* VTb = (unsigned short*)(ws + 56623104);      // 16 MB
  unsigned short* PKt = (unsigned short*)(ws + 73400320);      // 128 KB
  unsigned short* Rb  = (unsigned short*)(ws + 73531392);      // 16 MB (bf16)
  float* KVp = (float*)(ws);                                   // aliases Xb (dead after gemm)
  float* GNp = (float*)(ws + 90308608);                        // 4 KB
  float* MuS = (float*)(ws + 90312704);                        // 64 B

  k_cvt    <<<dim3(3072),    dim3(256), 0, stream>>>(x, w, pk, Xb, WTb, PKt);
  k_gemm   <<<dim3(24, 64),  dim3(256), 0, stream>>>(Xb, WTb, Qb, Kb, VTb);
  k_attn   <<<dim3(4, 128),  dim3(256), 0, stream>>>(Qb, Kb, VTb, PKt, Rb, GNp);
  k_kvpart <<<dim3(4, 128),  dim3(256), 0, stream>>>(Kb, VTb, KVp);
  k_kvfin  <<<dim3(256),     dim3(256), 0, stream>>>(KVp, pk, out + 8388608, GNp, MuS);
  k_gnnorm <<<dim3(1024),    dim3(256), 0, stream>>>(Rb, MuS, gw, gb, out);
}

// Round 7
// 161.006 us; speedup vs baseline: 1.4367x; 1.0161x over previous
//
#include <hip/hip_runtime.h>

// ChunkwiseRetention: B=8 T=1024 C=1024 NH=16 HD=64
// out[b,t,h*64+d] = GN_b(r)*w[h]+bias[h],  r = (QK^T ∘ decay)V + 1024*Q@past_kv
// current_kv[h] = gamma_h*past_kv[h] + mean_b(K^T V)

#define TKN 8192
#define N3  3072

typedef short short8 __attribute__((ext_vector_type(8)));
typedef float f32x4 __attribute__((ext_vector_type(4)));

static __device__ __forceinline__ unsigned short f2bf(float f){
  unsigned int u = __float_as_uint(f);
  u += 0x7FFFu + ((u >> 16) & 1u);
  return (unsigned short)(u >> 16);
}
static __device__ __forceinline__ float bf2f(unsigned short s){
  return __uint_as_float(((unsigned int)s) << 16);
}
static __device__ __forceinline__ void g2lds16(const void* g, void* l){
  __builtin_amdgcn_global_load_lds(
      (const __attribute__((address_space(1))) unsigned int*)g,
      (__attribute__((address_space(3))) unsigned int*)l, 16, 0, 0);
}

// ---------------- merged conversions ----------------
__global__ __launch_bounds__(256) void k_cvt(const float* __restrict__ x,
                                             const float* __restrict__ w,
                                             const float* __restrict__ pk,
                                             unsigned short* __restrict__ xb,
                                             unsigned short* __restrict__ wt,
                                             unsigned short* __restrict__ pkt){
  __shared__ float tile[64][65];
  const int bid = blockIdx.x;
  if (bid < 2048){
    const int n4 = TKN*1024/4;
    for (int idx = bid*256 + threadIdx.x; idx < n4; idx += 2048*256){
      float4 v = reinterpret_cast<const float4*>(x)[idx];
      ushort4 o;
      o.x = f2bf(v.x); o.y = f2bf(v.y); o.z = f2bf(v.z); o.w = f2bf(v.w);
      reinterpret_cast<ushort4*>(xb)[idx] = o;
    }
  } else if (bid < 2816){
    const int b2 = bid - 2048;
    const int n0 = (b2 % 48)*64, k0 = (b2 / 48)*64;
    const int tn = threadIdx.x & 63, t4 = threadIdx.x >> 6;
    for (int kk = t4; kk < 64; kk += 4)
      tile[kk][tn] = w[(k0+kk)*N3 + n0 + tn];
    __syncthreads();
    for (int nn = t4; nn < 64; nn += 4)
      wt[(n0+nn)*1024 + k0 + tn] = f2bf(tile[tn][nn]);
  } else {
    int i = (bid - 2816)*256 + threadIdx.x;
    int h = i >> 12, e = (i >> 6) & 63, d = i & 63;
    pkt[i] = f2bf(pk[(h<<12) + (d<<6) + e] * 1024.0f);
  }
}

// ---------------- QKV GEMM: 128x128, BK=32, triple-buffer, counted vmcnt ----------------
// XCD swizzle: n-fastest within each XCD's 192-block chunk -> 8 A-panels (2MB) per XCD L2.
__global__ __launch_bounds__(256, 3) void k_gemm(const unsigned short* __restrict__ A,
                                                 const unsigned short* __restrict__ Bt,
                                                 unsigned short* __restrict__ qb,
                                                 unsigned short* __restrict__ kb,
                                                 unsigned short* __restrict__ vtb){
  __shared__ unsigned short sm[24576];            // 48KB: A bufs 3x8KB | B bufs 3x8KB
  char* smb = (char*)sm;
  const int tid = threadIdx.x;
  const int lane = tid & 63, wid = tid >> 6;
  const int wm = wid >> 1, wn = wid & 1;
  const int n15 = lane & 15, l4 = lane >> 4;
  const int id = blockIdx.x;                      // 1536 blocks, 1536%8==0
  const int lin = (id & 7)*192 + (id >> 3);
  const int bm = lin / 24, bn = lin % 24;         // n-fastest within XCD chunk
  const int m0 = bm * 128;
  const int n0 = bn * 128;

  f32x4 acc[4][4] = {};

  // staging: dest line l0 = tid>>2 hosts row r0 = swap01(l0); slot tid&3 holds chunk c.
  const int l0 = tid >> 2;
  const int r0 = (l0 & ~3) | ((l0 & 1) << 1) | ((l0 >> 1) & 1);
  const int c0 = (((tid & 3) ^ ((tid >> 4) & 3)) << 3);   // chunk*8 elems
  #define STAGE(kt, b) do {                                                              \
    g2lds16(A  + (long)(m0 + r0)*1024      + (kt)*32 + c0, smb + (b)*8192 + tid*16);     \
    g2lds16(A  + (long)(m0 + 64 + r0)*1024 + (kt)*32 + c0, smb + (b)*8192 + 4096 + tid*16); \
    g2lds16(Bt + (long)(n0 + r0)*1024      + (kt)*32 + c0, smb + 24576 + (b)*8192 + tid*16); \
    g2lds16(Bt + (long)(n0 + 64 + r0)*1024 + (kt)*32 + c0, smb + 24576 + (b)*8192 + 4096 + tid*16); \
  } while(0)

  STAGE(0, 0);
  STAGE(1, 1);
  asm volatile("s_waitcnt vmcnt(4)" ::: "memory");
  __builtin_amdgcn_s_barrier();

  const int slb = (l4 ^ ((n15 >> 2) & 3)) << 4;   // slot byte (row-invariant)
  int cur = 0;
  for (int t = 0; t < 32; ++t){
    int nb = cur + 2; if (nb >= 3) nb -= 3;
    if (t < 30) STAGE(t + 2, nb);
    const char* ab = smb + cur*8192;
    const char* bb = smb + 24576 + cur*8192;
    short8 a[4], b[4];
    #pragma unroll
    for (int i = 0; i < 4; ++i){
      int ra = wm*64 + i*16 + n15;
      int rs = (ra & ~3) | ((ra & 1) << 1) | ((ra >> 1) & 1);
      a[i] = *(const short8*)(ab + rs*64 + slb);
      int rb = wn*64 + i*16 + n15;
      int rbs = (rb & ~3) | ((rb & 1) << 1) | ((rb >> 1) & 1);
      b[i] = *(const short8*)(bb + rbs*64 + slb);
    }
    __builtin_amdgcn_s_setprio(1);
    #pragma unroll
    for (int i = 0; i < 4; ++i)
      #pragma unroll
      for (int j = 0; j < 4; ++j)
        acc[i][j] = __builtin_amdgcn_mfma_f32_16x16x32_bf16(a[i], b[j], acc[i][j], 0, 0, 0);
    __builtin_amdgcn_s_setprio(0);
    if (t < 30) asm volatile("s_waitcnt vmcnt(4)" ::: "memory");
    else        asm volatile("s_waitcnt vmcnt(0)" ::: "memory");
    __builtin_amdgcn_s_barrier();
    cur = cur + 1; if (cur == 3) cur = 0;
  }
  #undef STAGE

  // conflict-free per-wave epilogue: 8KB scratch [64 rows][128B], XOR-swizzled
  const int bb2 = m0 >> 10;
  const int which = n0 >> 10;                     // 0=q 1=k 2=v
  const int cw = (n0 & 1023) + wn*64;
  const int h = cw >> 6;
  const long bh = (long)(bb2*16 + h);
  const int trow0 = (m0 & 1023) + wm*64;
  char* W = smb + wid*8192;

  if (which < 2){                                 // q,k row-major [b][h][t][64]
    unsigned short* dst = which ? kb : qb;
    #pragma unroll
    for (int mi = 0; mi < 4; ++mi)
      #pragma unroll
      for (int nf = 0; nf < 4; ++nf)
        #pragma unroll
        for (int r = 0; r < 4; ++r){
          int row = mi*16 + l4*4 + r;
          int colb = (nf*32 + 2*n15) ^ ((row & 7) << 4);
          *(unsigned short*)(W + row*128 + colb) = f2bf(acc[mi][nf][r]);
        }
    asm volatile("s_waitcnt lgkmcnt(0)" ::: "memory");
    #pragma unroll
    for (int hh = 0; hh < 2; ++hh)
      #pragma unroll
      for (int c2 = 0; c2 < 4; ++c2){
        int row = hh*32 + (lane >> 1);
        int off = ((lane & 1)*64 + c2*16) ^ ((row & 7) << 4);
        uint4 v = *(const uint4*)(W + row*128 + off);
        int dcol = (lane & 1)*32 + c2*8;
        *(uint4*)(&dst[(bh*1024 + trow0 + row)*64 + dcol]) = v;
      }
  } else {                                        // v transposed [b][h][d][t]
    #pragma unroll
    for (int mi = 0; mi < 4; ++mi)
      #pragma unroll
      for (int nf = 0; nf < 4; ++nf)
        #pragma unroll
        for (int r = 0; r < 4; ++r){
          int dl = nf*16 + n15;
          int row = mi*16 + l4*4 + r;
          int colb = (2*row) ^ ((dl & 7) << 4);
          *(unsigned short*)(W + dl*128 + colb) = f2bf(acc[mi][nf][r]);
        }
    asm volatile("s_waitcnt lgkmcnt(0)" ::: "memory");
    #pragma unroll
    for (int hh = 0; hh < 2; ++hh)
      #pragma unroll
      for (int c2 = 0; c2 < 4; ++c2){
        int dl = hh*32 + (lane >> 1);
        int off = ((lane & 1)*64 + c2*16) ^ ((dl & 7) << 4);
        uint4 v = *(const uint4*)(W + dl*128 + off);
        int tcol = (lane & 1)*32 + c2*8;
        *(uint4*)(&vtb[(bh*64 + dl)*1024 + trow0 + tcol]) = v;
      }
  }
}

// ---------------- attention: swapped QK^T, packed P-writes, coalesced R ----------------
// XCD swizzle: 4 qpair-blocks of one bh co-resident on one XCD (512 blocks, all resident).
__global__ __launch_bounds__(256) void k_attn(const unsigned short* __restrict__ qb,
                                              const unsigned short* __restrict__ kb,
                                              const unsigned short* __restrict__ vtb,
                                              const unsigned short* __restrict__ pkt,
                                              unsigned short* __restrict__ rb,
                                              float* __restrict__ gnp){
  __shared__ unsigned short Qs[8192];
  __shared__ unsigned short Kd[2][4096];
  __shared__ unsigned short Vd[2][4096];
  __shared__ unsigned short Ps[8192];
  __shared__ float gred[2][4];
  const int id = blockIdx.x;                      // 512 blocks, 512%8==0
  const int lin = (id & 7)*64 + (id >> 3);
  const int qpair = lin & 3;
  const int bh = lin >> 2;
  const int h = bh & 15;
  const int tid = threadIdx.x;
  const int lane = tid & 63, wid = tid >> 6;
  const int n15 = lane & 15, l4 = lane >> 4;
  const unsigned short* qp = qb + (long)bh*65536;
  const unsigned short* kp = kb + (long)bh*65536;
  const unsigned short* vp = vtb + (long)bh*65536;
  const float lg = log2f(1.0f - exp2f(-5.0f - (float)h));
  const int srow = tid >> 3, schunk = tid & 7;

  // gamma^{-(kv within tile)}: kv = i*16 + l4*4 + r
  float kvE[4][4];
  #pragma unroll
  for (int i = 0; i < 4; ++i)
    #pragma unroll
    for (int r = 0; r < 4; ++r)
      kvE[i][r] = exp2f(-lg * (float)(i*16 + l4*4 + r));

  float gs = 0.f, gq = 0.f;
  unsigned short* rp = rb + (long)bh*65536;

  for (int p = 0; p < 2; ++p){
    const int qt = p ? (7 - qpair) : qpair;
    const int t0 = qt * 128;
    for (int c = 0; c < 4; ++c){
      int r = c*32 + srow;
      int src = schunk ^ (r & 7);
      g2lds16(qp + (long)(t0 + r)*64 + src*8, (char*)Qs + c*4096 + tid*16);
    }
    for (int c = 0; c < 2; ++c){
      int r = c*32 + srow;
      int src = schunk ^ (r & 7);
      g2lds16(pkt + (long)(h*64 + r)*64 + src*8, (char*)Ps + c*4096 + tid*16);
      g2lds16(kp + (long)r*64 + src*8, (char*)Kd[0] + c*4096 + tid*16);
      g2lds16(vp + (long)r*1024 + src*8, (char*)Vd[0] + c*4096 + tid*16);
    }
    asm volatile("s_waitcnt vmcnt(0)" ::: "memory");
    __syncthreads();

    short8 aq[2][2];
    #pragma unroll
    for (int mf = 0; mf < 2; ++mf)
      #pragma unroll
      for (int kk = 0; kk < 2; ++kk){
        int r = wid*32 + mf*16 + n15;
        int sl = (kk*4 + l4) ^ (r & 7);
        aq[mf][kk] = *reinterpret_cast<const short8*>((const char*)Qs + r*128 + sl*16);
      }

    f32x4 o[2][4] = {};                           // cross = Q @ (pk^T*1024), [t][e]
    #pragma unroll
    for (int kk = 0; kk < 2; ++kk){
      short8 bpk[4];
      #pragma unroll
      for (int nf = 0; nf < 4; ++nf){
        int r = nf*16 + n15;
        int sl = (kk*4 + l4) ^ (r & 7);
        bpk[nf] = *reinterpret_cast<const short8*>((const char*)Ps + r*128 + sl*16);
      }
      #pragma unroll
      for (int mf = 0; mf < 2; ++mf)
        #pragma unroll
        for (int nf = 0; nf < 4; ++nf)
          o[mf][nf] = __builtin_amdgcn_mfma_f32_16x16x32_bf16(aq[mf][kk], bpk[nf], o[mf][nf], 0,0,0);
    }
    __syncthreads();                              // Ps free for P

    const int jmax = 2*qt + 1;
    int cur = 0;
    for (int j = 0; j <= jmax; ++j){
      const int kv0 = j*64;
      if (j < jmax){
        const int kvn = kv0 + 64;
        for (int c = 0; c < 2; ++c){
          int r = c*32 + srow;
          int src = schunk ^ (r & 7);
          g2lds16(kp + (long)(kvn + r)*64 + src*8, (char*)Kd[cur^1] + c*4096 + tid*16);
          g2lds16(vp + (long)r*1024 + kvn + src*8, (char*)Vd[cur^1] + c*4096 + tid*16);
        }
      }
      const bool active = (kv0 <= t0 + wid*32 + 31);   // wave-uniform
      if (active){
        // S^T = K Q^T : sT[i over kv][mf over t]; lane: t = wid*32+mf*16+n15, kv = i*16+l4*4+r
        f32x4 sT[4][2] = {};
        #pragma unroll
        for (int kk = 0; kk < 2; ++kk){
          short8 bk[4];
          #pragma unroll
          for (int i = 0; i < 4; ++i){
            int r = i*16 + n15;
            int sl = (kk*4 + l4) ^ (r & 7);
            bk[i] = *reinterpret_cast<const short8*>((const char*)Kd[cur] + r*128 + sl*16);
          }
          #pragma unroll
          for (int i = 0; i < 4; ++i)
            #pragma unroll
            for (int mf = 0; mf < 2; ++mf)
              sT[i][mf] = __builtin_amdgcn_mfma_f32_16x16x32_bf16(bk[i], aq[mf][kk], sT[i][mf], 0,0,0);
        }
        // decay + pack 4 kv into b64, write P [t][kv] swizzled
        const bool diag = (kv0 + 63 > t0 + wid*32);
        #pragma unroll
        for (int mf = 0; mf < 2; ++mf){
          const int trow = wid*32 + mf*16 + n15;
          const float rowE = exp2f(lg * (float)(t0 + trow - kv0));
          char* wb = (char*)Ps + trow*128;
          const int swz = (trow & 7) << 4;
          #pragma unroll
          for (int i = 0; i < 4; ++i){
            float v0 = sT[i][mf][0] * (rowE * kvE[i][0]);
            float v1 = sT[i][mf][1] * (rowE * kvE[i][1]);
            float v2 = sT[i][mf][2] * (rowE * kvE[i][2]);
            float v3 = sT[i][mf][3] * (rowE * kvE[i][3]);
            if (diag){
              int dd = (t0 + trow) - (kv0 + i*16 + l4*4);
              if (dd < 0) v0 = 0.f;
              if (dd < 1) v1 = 0.f;
              if (dd < 2) v2 = 0.f;
              if (dd < 3) v3 = 0.f;
            }
            uint2 pw;
            pw.x = (unsigned int)f2bf(v0) | ((unsigned int)f2bf(v1) << 16);
            pw.y = (unsigned int)f2bf(v2) | ((unsigned int)f2bf(v3) << 16);
            *(uint2*)(wb + ((i*32 + l4*8) ^ swz)) = pw;
          }
        }
        // O += P @ V
        #pragma unroll
        for (int kk = 0; kk < 2; ++kk){
          short8 ap[2], bv[4];
          #pragma unroll
          for (int mf = 0; mf < 2; ++mf){
            int r = wid*32 + mf*16 + n15;
            int sl = (kk*4 + l4) ^ (r & 7);
            ap[mf] = *reinterpret_cast<const short8*>((const char*)Ps + r*128 + sl*16);
          }
          #pragma unroll
          for (int nf = 0; nf < 4; ++nf){
            int r = nf*16 + n15;
            int sl = (kk*4 + l4) ^ (r & 7);
            bv[nf] = *reinterpret_cast<const short8*>((const char*)Vd[cur] + r*128 + sl*16);
          }
          #pragma unroll
          for (int mf = 0; mf < 2; ++mf)
            #pragma unroll
            for (int nf = 0; nf < 4; ++nf)
              o[mf][nf] = __builtin_amdgcn_mfma_f32_16x16x32_bf16(ap[mf], bv[nf], o[mf][nf], 0,0,0);
        }
      }
      asm volatile("s_waitcnt vmcnt(0)" ::: "memory");
      __syncthreads();
      cur ^= 1;
    }
    // epilogue: o -> Ps (wave-local, swizzled) -> coalesced global; + GN partials
    #pragma unroll
    for (int mf = 0; mf < 2; ++mf)
      #pragma unroll
      for (int nf = 0; nf < 4; ++nf)
        #pragma unroll
        for (int r = 0; r < 4; ++r){
          int trow = wid*32 + mf*16 + l4*4 + r;
          int d = nf*16 + n15;
          float v = o[mf][nf][r];
          gs += v; gq += v*v;
          *(unsigned short*)((char*)Ps + trow*128 + ((2*d) ^ ((trow & 7) << 4))) = f2bf(v);
        }
    asm volatile("s_waitcnt lgkmcnt(0)" ::: "memory");
    #pragma unroll
    for (int rr = 0; rr < 4; ++rr){
      int row = wid*32 + rr*8 + (lane >> 3);
      int off = (((lane & 7) << 4) ^ ((row & 7) << 4));
      uint4 v = *(const uint4*)((const char*)Ps + row*128 + off);
      *(uint4*)(rp + (long)(t0 + row)*64 + ((lane & 7) << 3)) = v;
    }
    __syncthreads();                              // protect Ps before next p staging
  }
  #pragma unroll
  for (int off = 32; off > 0; off >>= 1){
    gs += __shfl_down(gs, off);
    gq += __shfl_down(gq, off);
  }
  if (lane == 0){ gred[0][wid] = gs; gred[1][wid] = gq; }
  __syncthreads();
  if (tid == 0){
    gnp[(bh*4 + qpair)*2]   = gred[0][0]+gred[0][1]+gred[0][2]+gred[0][3];
    gnp[(bh*4 + qpair)*2+1] = gred[1][0]+gred[1][1]+gred[1][2]+gred[1][3];
  }
}

// ---------------- K^T V partials (LDS-transpose vector-FMA) ----------------
__global__ __launch_bounds__(256) void k_kvpart(const unsigned short* __restrict__ kb,
                                                const unsigned short* __restrict__ vtb,
                                                float* __restrict__ part){
  __shared__ unsigned short Kt[64*64];            // [t][d]
  __shared__ unsigned int   Vt32[64*33];          // [e][t] padded rows (66 ushorts)
  const int id = blockIdx.x;                      // 512 blocks
  const int lin = (id & 7)*64 + (id >> 3);
  const int tc = lin & 3, bh = lin >> 2;
  const int tid = threadIdx.x;
  const int d0 = (tid >> 4) << 2;
  const int e0 = (tid & 15) << 2;
  const unsigned short* kp = kb + (long)bh*65536;
  const unsigned short* vp = vtb + (long)bh*65536;
  float acc[4][4] = {{0.f}};
  for (int tt = 0; tt < 4; ++tt){
    const int tb = tc*256 + tt*64;
    __syncthreads();
    {
      int rr0 = tid >> 3, off = (tid & 7) * 8;
      for (int c = 0; c < 2; ++c){
        int r = c*32 + rr0;
        *reinterpret_cast<uint4*>(&Kt[r*64 + off]) =
            *reinterpret_cast<const uint4*>(&kp[(long)(tb + r)*64 + off]);
        uint4 vv = *reinterpret_cast<const uint4*>(&vp[(long)r*1024 + tb + off]);
        unsigned int* dv = &Vt32[r*33 + (off >> 1)];
        dv[0] = vv.x; dv[1] = vv.y; dv[2] = vv.z; dv[3] = vv.w;
      }
    }
    __syncthreads();
    const unsigned short* Vt = (const unsigned short*)Vt32;
    for (int t = 0; t < 64; ++t){
      float kv[4], vv[4];
      #pragma unroll
      for (int i = 0; i < 4; ++i) kv[i] = bf2f(Kt[t*64 + d0 + i]);
      #pragma unroll
      for (int i = 0; i < 4; ++i) vv[i] = bf2f(Vt[(e0 + i)*66 + t]);
      #pragma unroll
      for (int i = 0; i < 4; ++i)
        #pragma unroll
        for (int j = 0; j < 4; ++j) acc[i][j] += kv[i]*vv[j];
    }
  }
  float* pp = part + ((long)(tc*128 + bh) << 12);
  for (int i = 0; i < 4; ++i)
    for (int j = 0; j < 4; ++j)
      pp[(d0+i)*64 + e0 + j] = acc[i][j];
}

// kvfin + GroupNorm stage-2 fused
__global__ __launch_bounds__(256) void k_kvfin(const float* __restrict__ part,
                                               const float* __restrict__ pk,
                                               float* __restrict__ okv,
                                               const float* __restrict__ gnp,
                                               float* __restrict__ musig){
  if (blockIdx.x == 0 && threadIdx.x < 8){
    int b = threadIdx.x;
    float S = 0.f, Q = 0.f;
    for (int g = 0; g < 64; ++g){ S += gnp[b*128 + g*2]; Q += gnp[b*128 + g*2 + 1]; }
    float mu  = S * (1.0f/1048576.0f);
    float var = Q * (1.0f/1048576.0f) - mu*mu;
    musig[b*2]   = mu;
    musig[b*2+1] = rsqrtf(var + 1e-5f);
  }
  int i = blockIdx.x*256 + threadIdx.x;           // 65536
  int h = i >> 12;
  float acc = 0.f;
  for (int tc = 0; tc < 4; ++tc)
    for (int b = 0; b < 8; ++b)
      acc += part[((long)(tc*128 + b*16 + h) << 12) + (i & 4095)];
  float gamma = 1.0f - exp2f(-5.0f - (float)h);
  okv[i] = gamma * pk[i] + acc * 0.125f;
}

__global__ __launch_bounds__(256) void k_gnnorm(const unsigned short* __restrict__ rbuf,
                                                const float* __restrict__ musig,
                                                const float* __restrict__ gw,
                                                const float* __restrict__ gb,
                                                float* __restrict__ out){
  const int n8 = TKN*1024/8;
  for (int idx = blockIdx.x*256 + threadIdx.x; idx < n8; idx += gridDim.x*256){
    int o = idx*8;
    int c = o & 1023;
    int t = (o >> 10) & 1023;
    int b = o >> 20;
    int h = c >> 6, d = c & 63;
    short8 v = *reinterpret_cast<const short8*>(rbuf + ((long)(b*16 + h) << 16) + t*64 + d);
    float rs = musig[b*2+1];
    float a = gw[h]*rs, b2 = gb[h] - musig[b*2]*a;
    float4 o0, o1;
    o0.x = bf2f((unsigned short)v[0])*a + b2;
    o0.y = bf2f((unsigned short)v[1])*a + b2;
    o0.z = bf2f((unsigned short)v[2])*a + b2;
    o0.w = bf2f((unsigned short)v[3])*a + b2;
    o1.x = bf2f((unsigned short)v[4])*a + b2;
    o1.y = bf2f((unsigned short)v[5])*a + b2;
    o1.z = bf2f((unsigned short)v[6])*a + b2;
    o1.w = bf2f((unsigned short)v[7])*a + b2;
    *reinterpret_cast<float4*>(out + o)     = o0;
    *reinterpret_cast<float4*>(out + o + 4) = o1;
  }
}

extern "C" void kernel_launch(void* const* d_in, const int* in_sizes, int n_in,
                              void* d_out, int out_size, void* d_ws, size_t ws_size,
                              hipStream_t stream){
  const float* x  = (const float*)d_in[0];
  const float* pk = (const float*)d_in[1];
  const float* w  = (const float*)d_in[2];
  const float* gw = (const float*)d_in[3];
  const float* gb = (const float*)d_in[4];
  float* out = (float*)d_out;
  char* ws = (char*)d_ws;

  unsigned short* Xb  = (unsigned short*)(ws);                 // 16 MB (aliased by KVp later)
  unsigned short* WTb = (unsigned short*)(ws + 16777216);      //  6 MB
  unsigned short* Qb  = (unsigned short*)(ws + 23068672);      // 16 MB
  unsigned short* Kb  = (unsigned short*)(ws + 39845888);      // 16 MB
  unsigned short* VTb = (unsigned short*)(ws + 56623104);      // 16 MB
  unsigned short* PKt = (unsigned short*)(ws + 73400320);      // 128 KB
  unsigned short* Rb  = (unsigned short*)(ws + 73531392);      // 16 MB (bf16)
  float* KVp = (float*)(ws);                                   // aliases Xb (dead after gemm)
  float* GNp = (float*)(ws + 90308608);                        // 4 KB
  float* MuS = (float*)(ws + 90312704);                        // 64 B

  k_cvt    <<<dim3(3072),    dim3(256), 0, stream>>>(x, w, pk, Xb, WTb, PKt);
  k_gemm   <<<dim3(1536),    dim3(256), 0, stream>>>(Xb, WTb, Qb, Kb, VTb);
  k_attn   <<<dim3(512),     dim3(256), 0, stream>>>(Qb, Kb, VTb, PKt, Rb, GNp);
  k_kvpart <<<dim3(512),     dim3(256), 0, stream>>>(Kb, VTb, KVp);
  k_kvfin  <<<dim3(256),     dim3(256), 0, stream>>>(KVp, pk, out + 8388608, GNp, MuS);
  k_gnnorm <<<dim3(1024),    dim3(256), 0, stream>>>(Rb, MuS, gw, gb, out);
}